// Round 9
// baseline (292.606 us; speedup 1.0000x reference)
//
#include <hip/hip_runtime.h>
#include <math.h>

#define THREADS 256
#define HIST_ILP 8
#define EPB_SHIFT 11   // edges per hist block = THREADS*HIST_ILP = 2048 = 1<<11

static inline int cdiv(long long a, long long b) { return (int)((a + b - 1) / b); }

typedef __attribute__((ext_vector_type(8))) short bf16x8;
typedef __attribute__((ext_vector_type(4))) float f32x4;

__device__ inline unsigned f2bf_rne_u(float f) {
    unsigned u = __builtin_bit_cast(unsigned, f);
    return (u + 0x7FFFu + ((u >> 16) & 1u)) >> 16;
}
__device__ inline float bfu2f(unsigned h) {
    unsigned u = h << 16;
    return __builtin_bit_cast(float, u);
}

// ================= device bodies =================

// one 64-lane unit builds one (hi,lo) W-fragment pair
__device__ __forceinline__ void bfrag_unit(const float* __restrict__ W, short* __restrict__ frag,
                                           int NCT, int ctks, int lane) {
    int Nn = NCT * 16;
    int ct = ctks % NCT;
    int ks = ctks / NCT;
    int colc = ct * 16 + (lane & 15);
    int kbase = ks * 32 + (lane >> 4) * 8;
    short* base = frag + (size_t)ctks * 1024 + lane * 8;
    #pragma unroll
    for (int j = 0; j < 8; ++j) {
        float v = W[(size_t)(kbase + j) * Nn + colc];
        unsigned h = f2bf_rne_u(v);
        base[j] = (short)h;
        base[512 + j] = (short)f2bf_rne_u(v - bfu2f(h));
    }
}

// split-bf16 MFMA GEMM body with depth-1 A-prefetch: writes H = bf16(A @ W).
template<int NCT, int KS>
__device__ __forceinline__ void gemm_body(const float* __restrict__ A, const short* __restrict__ Bfrag,
                                          unsigned short* __restrict__ H, int M, int blk) {
    constexpr int K = KS * 32;
    constexpr int Nn = NCT * 16;
    const int lane = threadIdx.x & 63;
    const int wave = threadIdx.x >> 6;
    const int rowBase = blk * 128 + wave * 32;
    const int kgrp = (lane >> 4) * 8;

    const float* ap0;
    const float* ap1;
    {
        int r0 = rowBase + (lane & 15);      if (r0 >= M) r0 = M - 1;
        int r1 = rowBase + (lane & 15) + 16; if (r1 >= M) r1 = M - 1;
        ap0 = A + (size_t)r0 * K + kgrp;
        ap1 = A + (size_t)r1 * K + kgrp;
    }

    f32x4 acc[2][NCT] = {};

    float4 c00 = *(const float4*)(ap0);
    float4 c01 = *(const float4*)(ap0 + 4);
    float4 c10 = *(const float4*)(ap1);
    float4 c11 = *(const float4*)(ap1 + 4);

    for (int ks = 0; ks < KS; ++ks) {
        float4 n00, n01, n10, n11;
        if (ks + 1 < KS) {
            const float* p0 = ap0 + (size_t)(ks + 1) * 32;
            const float* p1 = ap1 + (size_t)(ks + 1) * 32;
            n00 = *(const float4*)(p0);
            n01 = *(const float4*)(p0 + 4);
            n10 = *(const float4*)(p1);
            n11 = *(const float4*)(p1 + 4);
        }
        bf16x8 ahi[2], alo[2];
        {
            float av0[8] = {c00.x, c00.y, c00.z, c00.w, c01.x, c01.y, c01.z, c01.w};
            float av1[8] = {c10.x, c10.y, c10.z, c10.w, c11.x, c11.y, c11.z, c11.w};
            #pragma unroll
            for (int j = 0; j < 8; ++j) {
                unsigned h0 = f2bf_rne_u(av0[j]);
                ahi[0][j] = (short)h0;
                alo[0][j] = (short)f2bf_rne_u(av0[j] - bfu2f(h0));
                unsigned h1 = f2bf_rne_u(av1[j]);
                ahi[1][j] = (short)h1;
                alo[1][j] = (short)f2bf_rne_u(av1[j] - bfu2f(h1));
            }
        }
        #pragma unroll
        for (int ct = 0; ct < NCT; ++ct) {
            const short* bp = Bfrag + (size_t)(ks * NCT + ct) * 1024 + lane * 8;
            bf16x8 bhi = *(const bf16x8*)bp;
            bf16x8 blo = *(const bf16x8*)(bp + 512);
            #pragma unroll
            for (int t = 0; t < 2; ++t) {
                acc[t][ct] = __builtin_amdgcn_mfma_f32_16x16x32_bf16(ahi[t], bhi, acc[t][ct], 0, 0, 0);
                acc[t][ct] = __builtin_amdgcn_mfma_f32_16x16x32_bf16(ahi[t], blo, acc[t][ct], 0, 0, 0);
                acc[t][ct] = __builtin_amdgcn_mfma_f32_16x16x32_bf16(alo[t], bhi, acc[t][ct], 0, 0, 0);
            }
        }
        c00 = n00; c01 = n01; c10 = n10; c11 = n11;
    }

    // C/D layout: col = lane&15, row(within 16-tile) = (lane>>4)*4 + reg
    const int drow0 = rowBase + (lane >> 4) * 4;
    #pragma unroll
    for (int t = 0; t < 2; ++t) {
        #pragma unroll
        for (int r = 0; r < 4; ++r) {
            int row = drow0 + t * 16 + r;
            if (row < M) {
                unsigned short* hp = H + (size_t)row * Nn + (lane & 15);
                #pragma unroll
                for (int ct = 0; ct < NCT; ++ct)
                    hp[ct * 16] = (unsigned short)f2bf_rne_u(acc[t][ct][r]);
            }
        }
    }
}

// ================= kernels =================

// K0: [zero deg8 blocks | bfrag blocks]
__global__ __launch_bounds__(THREADS)
void zero_bfrag_kernel(int* __restrict__ deg8, int total8,
                       const float* __restrict__ W1, short* __restrict__ bf1,
                       const float* __restrict__ W2, short* __restrict__ bf2, int nbZero) {
    int b = (int)blockIdx.x;
    if (b < nbZero) {
        int base = (b * THREADS + (int)threadIdx.x) * 4;
        if (base + 3 < total8) {
            *(int4*)(deg8 + base) = make_int4(0, 0, 0, 0);
        } else {
            for (int i = base; i < total8; ++i) deg8[i] = 0;
        }
    } else {
        int u = (b - nbZero) * 4 + ((int)threadIdx.x >> 6);
        int lane = threadIdx.x & 63;
        if (u < 64) bfrag_unit(W1, bf1, 8, u, lane);
        else if (u < 80) bfrag_unit(W2, bf2, 4, u - 64, lane);
    }
}

// XCD-local 8-copy histogram: copy = blockIdx.x & 7 (blocks round-robin XCDs).
// rank[e] = copy-local rank; copy id recomputable as (e >> EPB_SHIFT) & 7.
__global__ __launch_bounds__(THREADS)
void hist8_kernel(const int* __restrict__ dst, int* __restrict__ deg8,
                  int* __restrict__ rank, int E, int N) {
    int b = (int)blockIdx.x;
    int* deg = deg8 + (size_t)(b & 7) * N;
    int base = (b << EPB_SHIFT) + (int)threadIdx.x * HIST_ILP;
    if (base + HIST_ILP - 1 < E) {
        int4 d0 = *(const int4*)(dst + base);
        int4 d1 = *(const int4*)(dst + base + 4);
        int4 r0, r1;
        r0.x = atomicAdd(&deg[d0.x], 1);
        r0.y = atomicAdd(&deg[d0.y], 1);
        r0.z = atomicAdd(&deg[d0.z], 1);
        r0.w = atomicAdd(&deg[d0.w], 1);
        r1.x = atomicAdd(&deg[d1.x], 1);
        r1.y = atomicAdd(&deg[d1.y], 1);
        r1.z = atomicAdd(&deg[d1.z], 1);
        r1.w = atomicAdd(&deg[d1.w], 1);
        *(int4*)(rank + base) = r0;
        *(int4*)(rank + base + 4) = r1;
    } else {
        for (int e = base; e < E; ++e) rank[e] = atomicAdd(&deg[dst[e]], 1);
    }
}

// ================= exclusive scan over summed deg8, fused dis =================

#define SCAN_BLOCK 256
#define SCAN_ITEMS 4   // 1024 elements per block

__global__ __launch_bounds__(SCAN_BLOCK)
void scan_block_kernel(const int* __restrict__ deg8, int* __restrict__ out,
                       int* __restrict__ blockSums, float* __restrict__ dis, int n) {
    __shared__ int sdata[SCAN_BLOCK];
    int base = blockIdx.x * (SCAN_BLOCK * SCAN_ITEMS);
    int tid = threadIdx.x;
    int v[SCAN_ITEMS];
    int sum = 0;
    #pragma unroll
    for (int k = 0; k < SCAN_ITEMS; ++k) {
        int idx = base + tid * SCAN_ITEMS + k;
        int s8 = 0;
        if (idx < n) {
            #pragma unroll
            for (int c = 0; c < 8; ++c) s8 += deg8[(size_t)c * n + idx];
            dis[idx] = rsqrtf((float)s8 + 1.0f);
        }
        v[k] = s8;
        sum += s8;
    }
    sdata[tid] = sum;
    __syncthreads();
    for (int off = 1; off < SCAN_BLOCK; off <<= 1) {
        int t = (tid >= off) ? sdata[tid - off] : 0;
        __syncthreads();
        sdata[tid] += t;
        __syncthreads();
    }
    if (tid == SCAN_BLOCK - 1) blockSums[blockIdx.x] = sdata[SCAN_BLOCK - 1];
    int run = (tid == 0) ? 0 : sdata[tid - 1];
    #pragma unroll
    for (int k = 0; k < SCAN_ITEMS; ++k) {
        int idx = base + tid * SCAN_ITEMS + k;
        if (idx < n) out[idx] = run;
        run += v[k];
    }
}

__global__ __launch_bounds__(SCAN_BLOCK)
void scan_sums_kernel(int* __restrict__ blockSums, int nB) {
    __shared__ int sdata[SCAN_BLOCK];
    int tid = threadIdx.x;
    sdata[tid] = (tid < nB) ? blockSums[tid] : 0;
    __syncthreads();
    for (int off = 1; off < SCAN_BLOCK; off <<= 1) {
        int t = (tid >= off) ? sdata[tid - off] : 0;
        __syncthreads();
        sdata[tid] += t;
        __syncthreads();
    }
    int excl = (tid == 0) ? 0 : sdata[tid - 1];
    if (tid < nB) blockSums[tid] = excl;
}

// finalize rowptr and emit rp8[c][node] = rowptr[node] + prefix_c(deg8[.][node])
__global__ __launch_bounds__(SCAN_BLOCK)
void scan_add_rp8_kernel(int* __restrict__ rowptr, const int* __restrict__ blockSums,
                         const int* __restrict__ deg8, int* __restrict__ rp8,
                         int n, int E) {
    int base = blockIdx.x * (SCAN_BLOCK * SCAN_ITEMS);
    int add = blockSums[blockIdx.x];
    #pragma unroll
    for (int k = 0; k < SCAN_ITEMS; ++k) {
        int idx = base + threadIdx.x * SCAN_ITEMS + k;
        if (idx < n) {
            int val = rowptr[idx] + add;
            rowptr[idx] = val;
            int run = val;
            #pragma unroll
            for (int c = 0; c < 8; ++c) {
                rp8[(size_t)c * n + idx] = run;
                run += deg8[(size_t)c * n + idx];
            }
        }
    }
    if (blockIdx.x == 0 && threadIdx.x == 0) rowptr[n] = E;
}

// CSR fill, atomic-free, 4 edges/thread; copy id recomputed from e
__global__ __launch_bounds__(THREADS)
void fill_col_rp8_kernel(const int* __restrict__ src, const int* __restrict__ dst,
                         const int* __restrict__ rank, const int* __restrict__ rp8,
                         int* __restrict__ col, int E, int N) {
    int base = ((int)blockIdx.x * THREADS + (int)threadIdx.x) * 4;
    if (base + 3 < E) {
        int c = (base >> EPB_SHIFT) & 7;   // 4-pack never crosses a 2048 boundary
        const int* rp = rp8 + (size_t)c * N;
        int4 d = *(const int4*)(dst + base);
        int4 r = *(const int4*)(rank + base);
        int4 s = *(const int4*)(src + base);
        col[rp[d.x] + r.x] = s.x;
        col[rp[d.y] + r.y] = s.y;
        col[rp[d.z] + r.z] = s.z;
        col[rp[d.w] + r.w] = s.w;
    } else {
        for (int e = base; e < E; ++e) {
            int c = (e >> EPB_SHIFT) & 7;
            col[rp8[(size_t)c * N + dst[e]] + rank[e]] = src[e];
        }
    }
}

// standalone GEMM
template<int NCT, int KS>
__global__ __launch_bounds__(THREADS)
void mfma_gemm_bf16out_kernel(const float* __restrict__ A, const short* __restrict__ Bfrag,
                              unsigned short* __restrict__ H, int M) {
    gemm_body<NCT, KS>(A, Bfrag, H, M, (int)blockIdx.x);
}

// ================= fused gather aggregation (bf16 UNSCALED rows) =================
// out_i = relu(di * (di*h_i + sum_s dis[s]*h_s) + b).

template<int F, int VEC>
__global__ __launch_bounds__(THREADS)
void gather_bf16_kernel(const unsigned short* __restrict__ g, const int* __restrict__ col,
                        const int* __restrict__ rowptr, const float* __restrict__ dis,
                        const float* __restrict__ bias, float* __restrict__ out, int N) {
    int wid = (int)((blockIdx.x * (long long)blockDim.x + threadIdx.x) >> 6);
    wid = __builtin_amdgcn_readfirstlane(wid);
    const int lane = threadIdx.x & 63;
    if (wid >= N) return;
    const float di = dis[wid];
    const int loff = lane * VEC;

    float acc0 = 0.0f, acc1 = 0.0f;

    auto loadrow = [&](int s) -> unsigned {
        const unsigned short* p = g + (size_t)s * F + loff;
        if (VEC == 2) return *(const unsigned*)p;
        else return (unsigned)*p;
    };
    auto addconv = [&](unsigned u, float w) {
        if (VEC == 2) {
            acc0 += w * bfu2f(u & 0xFFFFu);
            acc1 += w * __builtin_bit_cast(float, u & 0xFFFF0000u);
        } else {
            acc0 += w * bfu2f(u);
        }
    };

    // self-loop row (weight di)
    addconv(loadrow(wid), di);

    int start = __builtin_amdgcn_readfirstlane(rowptr[wid]);
    int end   = __builtin_amdgcn_readfirstlane(rowptr[wid + 1]);
    const int* c = col + start;
    int rem = end - start;

    if (rem >= 4) {
        int s0 = __builtin_amdgcn_readfirstlane(c[0]);
        int s1 = __builtin_amdgcn_readfirstlane(c[1]);
        int s2 = __builtin_amdgcn_readfirstlane(c[2]);
        int s3 = __builtin_amdgcn_readfirstlane(c[3]);
        float w0 = dis[s0], w1 = dis[s1], w2 = dis[s2], w3 = dis[s3];
        unsigned u0 = loadrow(s0), u1 = loadrow(s1), u2 = loadrow(s2), u3 = loadrow(s3);
        c += 4; rem -= 4;
        while (rem >= 4) {
            int t0 = __builtin_amdgcn_readfirstlane(c[0]);
            int t1 = __builtin_amdgcn_readfirstlane(c[1]);
            int t2 = __builtin_amdgcn_readfirstlane(c[2]);
            int t3 = __builtin_amdgcn_readfirstlane(c[3]);
            float x0 = dis[t0], x1 = dis[t1], x2 = dis[t2], x3 = dis[t3];
            unsigned v0 = loadrow(t0), v1 = loadrow(t1), v2 = loadrow(t2), v3 = loadrow(t3);
            addconv(u0, w0); addconv(u1, w1); addconv(u2, w2); addconv(u3, w3);
            u0 = v0; u1 = v1; u2 = v2; u3 = v3;
            w0 = x0; w1 = x1; w2 = x2; w3 = x3;
            c += 4; rem -= 4;
        }
        addconv(u0, w0); addconv(u1, w1); addconv(u2, w2); addconv(u3, w3);
    }
    while (rem > 0) {
        int s = __builtin_amdgcn_readfirstlane(c[0]);
        addconv(loadrow(s), dis[s]);
        ++c; --rem;
    }

    float* orow = out + (size_t)wid * F + loff;
    float v0 = di * acc0 + bias[loff];
    if (VEC == 2) {
        float v1 = di * acc1 + bias[loff + 1];
        float2 st = make_float2(fmaxf(v0, 0.0f), fmaxf(v1, 0.0f));
        *(float2*)orow = st;
    } else {
        *orow = fmaxf(v0, 0.0f);
    }
}

// ================= fallback fp32 GEMM + atomic path (round-0, verified) =================

#define BM 64
#define BN 64
#define BK 16

__global__ __launch_bounds__(THREADS)
void sgemm_kernel(const float* __restrict__ A, const float* __restrict__ B,
                  float* __restrict__ C, int M, int N, int K) {
    __shared__ float As[BK][BM + 1];
    __shared__ float Bs[BK][BN + 1];

    const int tid = threadIdx.x;
    const int tr = tid / 16;
    const int tc = tid % 16;
    const int rowBase = blockIdx.y * BM;
    const int colBase = blockIdx.x * BN;

    float acc[4][4] = {};

    for (int k0 = 0; k0 < K; k0 += BK) {
        #pragma unroll
        for (int i = tid; i < BM * BK; i += THREADS) {
            int r = i / BK, c = i % BK;
            int gr = rowBase + r;
            As[c][r] = (gr < M) ? A[(size_t)gr * K + k0 + c] : 0.0f;
        }
        #pragma unroll
        for (int i = tid; i < BK * BN; i += THREADS) {
            int r = i / BN, c = i % BN;
            Bs[r][c] = B[(size_t)(k0 + r) * N + colBase + c];
        }
        __syncthreads();

        #pragma unroll
        for (int k = 0; k < BK; ++k) {
            float a[4], b[4];
            #pragma unroll
            for (int m = 0; m < 4; ++m) a[m] = As[k][tr * 4 + m];
            #pragma unroll
            for (int n = 0; n < 4; ++n) b[n] = Bs[k][tc * 4 + n];
            #pragma unroll
            for (int m = 0; m < 4; ++m)
                #pragma unroll
                for (int n = 0; n < 4; ++n)
                    acc[m][n] += a[m] * b[n];
        }
        __syncthreads();
    }

    #pragma unroll
    for (int m = 0; m < 4; ++m) {
        int gr = rowBase + tr * 4 + m;
        if (gr >= M) continue;
        #pragma unroll
        for (int n = 0; n < 4; ++n) {
            C[(size_t)gr * N + colBase + tc * 4 + n] = acc[m][n];
        }
    }
}

__global__ __launch_bounds__(THREADS)
void init_agg_kernel(const float* __restrict__ h, const float* __restrict__ dis,
                     float* __restrict__ agg, int N, int F) {
    int i = blockIdx.x * blockDim.x + threadIdx.x;
    int total = N * (F / 4);
    if (i >= total) return;
    int node = i / (F / 4);
    float d = dis[node];
    float w = d * d;
    float4 v = ((const float4*)h)[i];
    v.x *= w; v.y *= w; v.z *= w; v.w *= w;
    ((float4*)agg)[i] = v;
}

__global__ __launch_bounds__(THREADS)
void edge_scatter_kernel(const float* __restrict__ h, const int* __restrict__ src,
                         const int* __restrict__ dst, const float* __restrict__ dis,
                         float* __restrict__ agg, int E, int F) {
    int lanesPerEdge = F / 4;
    int tid = blockIdx.x * blockDim.x + threadIdx.x;
    int e = tid / lanesPerEdge;
    int c = tid % lanesPerEdge;
    if (e >= E) return;
    int s = src[e];
    int d = dst[e];
    float w = dis[s] * dis[d];
    float4 hv = ((const float4*)(h + (size_t)s * F))[c];
    float* ap = agg + (size_t)d * F + (size_t)c * 4;
    atomicAdd(ap + 0, hv.x * w);
    atomicAdd(ap + 1, hv.y * w);
    atomicAdd(ap + 2, hv.z * w);
    atomicAdd(ap + 3, hv.w * w);
}

__global__ __launch_bounds__(THREADS)
void finalize_kernel(const float* __restrict__ agg, const float* __restrict__ b,
                     float* __restrict__ out, int N, int F) {
    int i = blockIdx.x * blockDim.x + threadIdx.x;
    int total = N * (F / 4);
    if (i >= total) return;
    int c4 = i % (F / 4);
    float4 bv = ((const float4*)b)[c4];
    float4 v = ((const float4*)agg)[i];
    v.x = fmaxf(v.x + bv.x, 0.0f);
    v.y = fmaxf(v.y + bv.y, 0.0f);
    v.z = fmaxf(v.z + bv.z, 0.0f);
    v.w = fmaxf(v.w + bv.w, 0.0f);
    ((float4*)out)[i] = v;
}

__global__ __launch_bounds__(THREADS)
void fdeg_kernel(const int* __restrict__ dst, float* __restrict__ deg, int E) {
    int i = blockIdx.x * blockDim.x + threadIdx.x;
    if (i < E) atomicAdd(&deg[dst[i]], 1.0f);
}

__global__ __launch_bounds__(THREADS)
void fdis_kernel(float* __restrict__ deg, int N) {
    int i = blockIdx.x * blockDim.x + threadIdx.x;
    if (i < N) deg[i] = rsqrtf(deg[i] + 1.0f);
}

// ================= launch =================

extern "C" void kernel_launch(void* const* d_in, const int* in_sizes, int n_in,
                              void* d_out, int out_size, void* d_ws, size_t ws_size,
                              hipStream_t stream) {
    const float* x  = (const float*)d_in[0];
    const int*   ei = (const int*)d_in[1];
    const float* W1 = (const float*)d_in[2];
    const float* b1 = (const float*)d_in[3];
    const float* W2 = (const float*)d_in[4];
    const float* b2 = (const float*)d_in[5];

    const int E    = in_sizes[1] / 2;
    const int hid  = in_sizes[3];            // 128
    const int outc = in_sizes[5];            // 64
    const int inc  = in_sizes[2] / hid;      // 256
    const int N    = in_sizes[0] / inc;      // 100000

    const int* src = ei;
    const int* dst = ei + E;
    float* out = (float*)d_out;
    char* ws = (char*)d_ws;

    auto al = [](size_t v) { return (v + 255) & ~(size_t)255; };
    size_t o_dis  = 0;
    size_t o_deg8 = al(o_dis + (size_t)N * 4);
    size_t o_rp   = al(o_deg8 + (size_t)N * 32);
    size_t o_rp8  = al(o_rp + ((size_t)N + 1) * 4);
    size_t o_bs   = al(o_rp8 + (size_t)N * 32);
    size_t o_col  = al(o_bs + 4096);
    size_t o_rank = al(o_col + (size_t)E * 4);
    size_t o_bf1  = al(o_rank + (size_t)E * 4);
    size_t o_bf2  = al(o_bf1 + 131072);                // 8*8*1024 shorts
    size_t o_G    = al(o_bf2 + 32768);                 // 4*4*1024 shorts
    size_t o_B    = al(o_G + (size_t)N * hid * 2);     // h rows (bf16)
    size_t need   = o_B + (size_t)N * hid * 4;         // out1 (fp32)

    if (ws_size >= need && N <= SCAN_BLOCK * SCAN_BLOCK * SCAN_ITEMS &&
        hid == 128 && outc == 64 && inc == 256) {
        // ---------- CSR gather + MFMA path ----------
        float* dis    = (float*)(ws + o_dis);
        int*   deg8   = (int*)(ws + o_deg8);
        int*   rowptr = (int*)(ws + o_rp);
        int*   rp8    = (int*)(ws + o_rp8);
        int*   bsums  = (int*)(ws + o_bs);
        int*   col    = (int*)(ws + o_col);
        int*   rank   = (int*)(ws + o_rank);
        short* bf1    = (short*)(ws + o_bf1);
        short* bf2    = (short*)(ws + o_bf2);
        unsigned short* gbuf = (unsigned short*)(ws + o_G);  // h1 bf16 (N*128), later h2 (N*64)
        float* out1   = (float*)(ws + o_B);     // fp32 layer-1 output

        const int nbZero  = cdiv((long long)N * 8, 4 * THREADS);
        const int nbHist  = cdiv(E, THREADS * HIST_ILP);
        const int nbGemm1 = cdiv(N, 128);
        const int nbFill  = cdiv(E, 4 * THREADS);

        // K0: zero deg8 || weight fragments
        zero_bfrag_kernel<<<nbZero + 20, THREADS, 0, stream>>>(deg8, N * 8, W1, bf1, W2, bf2, nbZero);

        // XCD-local 8-copy histogram
        hist8_kernel<<<nbHist, THREADS, 0, stream>>>(dst, deg8, rank, E, N);

        // layer-1 GEMM (prefetched)
        mfma_gemm_bf16out_kernel<8, 8><<<nbGemm1, THREADS, 0, stream>>>(x, bf1, gbuf, N);

        // rowptr = exclusive_scan(sum deg8); dis fused; rp8 emitted in scan_add
        int nB = cdiv(N, SCAN_BLOCK * SCAN_ITEMS);
        scan_block_kernel<<<nB, SCAN_BLOCK, 0, stream>>>(deg8, rowptr, bsums, dis, N);
        scan_sums_kernel<<<1, SCAN_BLOCK, 0, stream>>>(bsums, nB);
        scan_add_rp8_kernel<<<nB, SCAN_BLOCK, 0, stream>>>(rowptr, bsums, deg8, rp8, N, E);

        // CSR fill (atomic-free)
        fill_col_rp8_kernel<<<nbFill, THREADS, 0, stream>>>(src, dst, rank, rp8, col, E, N);

        // ---- layer 1 gather ----
        gather_bf16_kernel<128, 2><<<cdiv((long long)N * 64, THREADS), THREADS, 0, stream>>>(
            gbuf, col, rowptr, dis, b1, out1, N);

        // ---- layer 2 ----
        mfma_gemm_bf16out_kernel<4, 4><<<cdiv(N, 128), THREADS, 0, stream>>>(out1, bf2, gbuf, N);
        gather_bf16_kernel<64, 1><<<cdiv((long long)N * 64, THREADS), THREADS, 0, stream>>>(
            gbuf, col, rowptr, dis, b2, out, N);
        return;
    }

    // ---------- fallback: round-0 atomic path ----------
    float* dis = (float*)ws;
    size_t off1 = ((size_t)N * 4 + 255) & ~(size_t)255;
    float* h1 = (float*)(ws + off1);
    size_t off2 = off1 + ((((size_t)N * hid * 4) + 255) & ~(size_t)255);
    float* agg1 = (float*)(ws + off2);
    float* h2   = agg1;
    float* agg2 = agg1 + (size_t)N * outc;

    hipMemsetAsync(dis, 0, (size_t)N * 4, stream);
    fdeg_kernel<<<cdiv(E, THREADS), THREADS, 0, stream>>>(dst, dis, E);
    fdis_kernel<<<cdiv(N, THREADS), THREADS, 0, stream>>>(dis, N);

    {
        dim3 grid(hid / BN, cdiv(N, BM));
        sgemm_kernel<<<grid, THREADS, 0, stream>>>(x, W1, h1, N, hid, inc);
    }
    init_agg_kernel<<<cdiv((long long)N * hid / 4, THREADS), THREADS, 0, stream>>>(h1, dis, agg1, N, hid);
    edge_scatter_kernel<<<cdiv((long long)E * (hid / 4), THREADS), THREADS, 0, stream>>>(
        h1, src, dst, dis, agg1, E, hid);
    finalize_kernel<<<cdiv((long long)N * hid / 4, THREADS), THREADS, 0, stream>>>(agg1, b1, h1, N, hid);

    {
        dim3 grid(outc / BN, cdiv(N, BM));
        sgemm_kernel<<<grid, THREADS, 0, stream>>>(h1, W2, h2, N, outc, hid);
    }
    init_agg_kernel<<<cdiv((long long)N * outc / 4, THREADS), THREADS, 0, stream>>>(h2, dis, agg2, N, outc);
    edge_scatter_kernel<<<cdiv((long long)E * (outc / 4), THREADS), THREADS, 0, stream>>>(
        h2, src, dst, dis, agg2, E, outc);
    finalize_kernel<<<cdiv((long long)N * outc / 4, THREADS), THREADS, 0, stream>>>(agg2, b2, out, N, outc);
}

// Round 10
// 290.140 us; speedup vs baseline: 1.0085x; 1.0085x over previous
//
#include <hip/hip_runtime.h>
#include <math.h>

#define THREADS 256
#define HIST_ILP 8
#define EPB_SHIFT 11   // edges per hist block = THREADS*HIST_ILP = 2048 = 1<<11

static inline int cdiv(long long a, long long b) { return (int)((a + b - 1) / b); }

typedef __attribute__((ext_vector_type(8))) short bf16x8;
typedef __attribute__((ext_vector_type(4))) float f32x4;

__device__ inline unsigned f2bf_rne_u(float f) {
    unsigned u = __builtin_bit_cast(unsigned, f);
    return (u + 0x7FFFu + ((u >> 16) & 1u)) >> 16;
}
__device__ inline float bfu2f(unsigned h) {
    unsigned u = h << 16;
    return __builtin_bit_cast(float, u);
}

// ================= device bodies =================

// one 64-lane unit builds one (hi,lo) W-fragment pair
__device__ __forceinline__ void bfrag_unit(const float* __restrict__ W, short* __restrict__ frag,
                                           int NCT, int ctks, int lane) {
    int Nn = NCT * 16;
    int ct = ctks % NCT;
    int ks = ctks / NCT;
    int colc = ct * 16 + (lane & 15);
    int kbase = ks * 32 + (lane >> 4) * 8;
    short* base = frag + (size_t)ctks * 1024 + lane * 8;
    #pragma unroll
    for (int j = 0; j < 8; ++j) {
        float v = W[(size_t)(kbase + j) * Nn + colc];
        unsigned h = f2bf_rne_u(v);
        base[j] = (short)h;
        base[512 + j] = (short)f2bf_rne_u(v - bfu2f(h));
    }
}

// XCD-local 8-copy histogram body. copy passed in (derived from GLOBAL block id,
// which round-robins XCDs); copy stored in rank[31:28] so fill can decode it.
__device__ __forceinline__ void hist8_body(const int* __restrict__ dst, int* __restrict__ deg8,
                                           int* __restrict__ rank, int E, int N,
                                           int hb, int copy) {
    int* deg = deg8 + (size_t)copy * N;
    const int chi = copy << 28;
    int base = (hb << EPB_SHIFT) + (int)threadIdx.x * HIST_ILP;
    if (base + HIST_ILP - 1 < E) {
        int4 d0 = *(const int4*)(dst + base);
        int4 d1 = *(const int4*)(dst + base + 4);
        int4 r0, r1;
        r0.x = atomicAdd(&deg[d0.x], 1) | chi;
        r0.y = atomicAdd(&deg[d0.y], 1) | chi;
        r0.z = atomicAdd(&deg[d0.z], 1) | chi;
        r0.w = atomicAdd(&deg[d0.w], 1) | chi;
        r1.x = atomicAdd(&deg[d1.x], 1) | chi;
        r1.y = atomicAdd(&deg[d1.y], 1) | chi;
        r1.z = atomicAdd(&deg[d1.z], 1) | chi;
        r1.w = atomicAdd(&deg[d1.w], 1) | chi;
        *(int4*)(rank + base) = r0;
        *(int4*)(rank + base + 4) = r1;
    } else {
        for (int e = base; e < E; ++e) rank[e] = atomicAdd(&deg[dst[e]], 1) | chi;
    }
}

// CSR fill, atomic-free, 4 edges/thread; copy decoded from rank[31:28]
__device__ __forceinline__ void fill_body(const int* __restrict__ src, const int* __restrict__ dst,
                                          const int* __restrict__ rank, const int* __restrict__ rp8,
                                          int* __restrict__ col, int E, int N, int blk) {
    int base = (blk * THREADS + (int)threadIdx.x) * 4;
    if (base + 3 < E) {
        int4 d = *(const int4*)(dst + base);
        int4 r = *(const int4*)(rank + base);
        int4 s = *(const int4*)(src + base);
        col[rp8[(size_t)(((unsigned)r.x) >> 28) * N + d.x] + (r.x & 0x0FFFFFFF)] = s.x;
        col[rp8[(size_t)(((unsigned)r.y) >> 28) * N + d.y] + (r.y & 0x0FFFFFFF)] = s.y;
        col[rp8[(size_t)(((unsigned)r.z) >> 28) * N + d.z] + (r.z & 0x0FFFFFFF)] = s.z;
        col[rp8[(size_t)(((unsigned)r.w) >> 28) * N + d.w] + (r.w & 0x0FFFFFFF)] = s.w;
    } else {
        for (int e = base; e < E; ++e) {
            int r = rank[e];
            col[rp8[(size_t)(((unsigned)r) >> 28) * N + dst[e]] + (r & 0x0FFFFFFF)] = src[e];
        }
    }
}

// split-bf16 MFMA GEMM body with depth-1 A-prefetch: writes H = bf16(A @ W).
template<int NCT, int KS>
__device__ __forceinline__ void gemm_body(const float* __restrict__ A, const short* __restrict__ Bfrag,
                                          unsigned short* __restrict__ H, int M, int blk) {
    constexpr int K = KS * 32;
    constexpr int Nn = NCT * 16;
    const int lane = threadIdx.x & 63;
    const int wave = threadIdx.x >> 6;
    const int rowBase = blk * 128 + wave * 32;
    const int kgrp = (lane >> 4) * 8;

    const float* ap0;
    const float* ap1;
    {
        int r0 = rowBase + (lane & 15);      if (r0 >= M) r0 = M - 1;
        int r1 = rowBase + (lane & 15) + 16; if (r1 >= M) r1 = M - 1;
        ap0 = A + (size_t)r0 * K + kgrp;
        ap1 = A + (size_t)r1 * K + kgrp;
    }

    f32x4 acc[2][NCT] = {};

    float4 c00 = *(const float4*)(ap0);
    float4 c01 = *(const float4*)(ap0 + 4);
    float4 c10 = *(const float4*)(ap1);
    float4 c11 = *(const float4*)(ap1 + 4);

    for (int ks = 0; ks < KS; ++ks) {
        float4 n00, n01, n10, n11;
        if (ks + 1 < KS) {
            const float* p0 = ap0 + (size_t)(ks + 1) * 32;
            const float* p1 = ap1 + (size_t)(ks + 1) * 32;
            n00 = *(const float4*)(p0);
            n01 = *(const float4*)(p0 + 4);
            n10 = *(const float4*)(p1);
            n11 = *(const float4*)(p1 + 4);
        }
        bf16x8 ahi[2], alo[2];
        {
            float av0[8] = {c00.x, c00.y, c00.z, c00.w, c01.x, c01.y, c01.z, c01.w};
            float av1[8] = {c10.x, c10.y, c10.z, c10.w, c11.x, c11.y, c11.z, c11.w};
            #pragma unroll
            for (int j = 0; j < 8; ++j) {
                unsigned h0 = f2bf_rne_u(av0[j]);
                ahi[0][j] = (short)h0;
                alo[0][j] = (short)f2bf_rne_u(av0[j] - bfu2f(h0));
                unsigned h1 = f2bf_rne_u(av1[j]);
                ahi[1][j] = (short)h1;
                alo[1][j] = (short)f2bf_rne_u(av1[j] - bfu2f(h1));
            }
        }
        __builtin_amdgcn_s_setprio(1);
        #pragma unroll
        for (int ct = 0; ct < NCT; ++ct) {
            const short* bp = Bfrag + (size_t)(ks * NCT + ct) * 1024 + lane * 8;
            bf16x8 bhi = *(const bf16x8*)bp;
            bf16x8 blo = *(const bf16x8*)(bp + 512);
            #pragma unroll
            for (int t = 0; t < 2; ++t) {
                acc[t][ct] = __builtin_amdgcn_mfma_f32_16x16x32_bf16(ahi[t], bhi, acc[t][ct], 0, 0, 0);
                acc[t][ct] = __builtin_amdgcn_mfma_f32_16x16x32_bf16(ahi[t], blo, acc[t][ct], 0, 0, 0);
                acc[t][ct] = __builtin_amdgcn_mfma_f32_16x16x32_bf16(alo[t], bhi, acc[t][ct], 0, 0, 0);
            }
        }
        __builtin_amdgcn_s_setprio(0);
        c00 = n00; c01 = n01; c10 = n10; c11 = n11;
    }

    const int drow0 = rowBase + (lane >> 4) * 4;
    #pragma unroll
    for (int t = 0; t < 2; ++t) {
        #pragma unroll
        for (int r = 0; r < 4; ++r) {
            int row = drow0 + t * 16 + r;
            if (row < M) {
                unsigned short* hp = H + (size_t)row * Nn + (lane & 15);
                #pragma unroll
                for (int ct = 0; ct < NCT; ++ct)
                    hp[ct * 16] = (unsigned short)f2bf_rne_u(acc[t][ct][r]);
            }
        }
    }
}

// ================= kernels =================

// K0: [zero deg8 blocks | bfrag blocks]
__global__ __launch_bounds__(THREADS)
void zero_bfrag_kernel(int* __restrict__ deg8, int total8,
                       const float* __restrict__ W1, short* __restrict__ bf1,
                       const float* __restrict__ W2, short* __restrict__ bf2, int nbZero) {
    int b = (int)blockIdx.x;
    if (b < nbZero) {
        int base = (b * THREADS + (int)threadIdx.x) * 4;
        if (base + 3 < total8) {
            *(int4*)(deg8 + base) = make_int4(0, 0, 0, 0);
        } else {
            for (int i = base; i < total8; ++i) deg8[i] = 0;
        }
    } else {
        int u = (b - nbZero) * 4 + ((int)threadIdx.x >> 6);
        int lane = threadIdx.x & 63;
        if (u < 64) bfrag_unit(W1, bf1, 8, u, lane);
        else if (u < 80) bfrag_unit(W2, bf2, 4, u - 64, lane);
    }
}

// K1: [hist8 || gemm1 part A] Bresenham-interleaved
__global__ __launch_bounds__(THREADS)
void hist_gemmA_kernel(const int* __restrict__ dst, int* __restrict__ deg8,
                       int* __restrict__ rank, int E, int N,
                       const float* __restrict__ A, const short* __restrict__ Bfrag,
                       unsigned short* __restrict__ H, int M,
                       int nbHist, int nbGemm) {
    int b = (int)blockIdx.x;
    int total = nbHist + nbGemm;
    long long t = (long long)b * nbGemm;
    int gBefore = (int)(t / total);
    bool isG = (((long long)(b + 1) * nbGemm) / total) > gBefore;
    if (isG) gemm_body<8, 8>(A, Bfrag, H, M, gBefore);
    else     hist8_body(dst, deg8, rank, E, N, b - gBefore, b & 7);
}

// K2: [fill || gemm1 part B] Bresenham-interleaved
__global__ __launch_bounds__(THREADS)
void fill_gemmB_kernel(const int* __restrict__ src, const int* __restrict__ dst,
                       const int* __restrict__ rank, const int* __restrict__ rp8,
                       int* __restrict__ col, int E, int N,
                       const float* __restrict__ A, const short* __restrict__ Bfrag,
                       unsigned short* __restrict__ H, int M, int gemmOff,
                       int nbFill, int nbGemm) {
    int b = (int)blockIdx.x;
    int total = nbFill + nbGemm;
    long long t = (long long)b * nbGemm;
    int gBefore = (int)(t / total);
    bool isG = (((long long)(b + 1) * nbGemm) / total) > gBefore;
    if (isG) gemm_body<8, 8>(A, Bfrag, H, M, gemmOff + gBefore);
    else     fill_body(src, dst, rank, rp8, col, E, N, b - gBefore);
}

// standalone GEMM
template<int NCT, int KS>
__global__ __launch_bounds__(THREADS)
void mfma_gemm_bf16out_kernel(const float* __restrict__ A, const short* __restrict__ Bfrag,
                              unsigned short* __restrict__ H, int M) {
    gemm_body<NCT, KS>(A, Bfrag, H, M, (int)blockIdx.x);
}

// ================= exclusive scan over summed deg8, fused dis =================

#define SCAN_BLOCK 256
#define SCAN_ITEMS 4   // 1024 elements per block

__global__ __launch_bounds__(SCAN_BLOCK)
void scan_block_kernel(const int* __restrict__ deg8, int* __restrict__ out,
                       int* __restrict__ blockSums, float* __restrict__ dis, int n) {
    __shared__ int sdata[SCAN_BLOCK];
    int base = blockIdx.x * (SCAN_BLOCK * SCAN_ITEMS);
    int tid = threadIdx.x;
    int v[SCAN_ITEMS];
    int sum = 0;
    #pragma unroll
    for (int k = 0; k < SCAN_ITEMS; ++k) {
        int idx = base + tid * SCAN_ITEMS + k;
        int s8 = 0;
        if (idx < n) {
            #pragma unroll
            for (int c = 0; c < 8; ++c) s8 += deg8[(size_t)c * n + idx];
            dis[idx] = rsqrtf((float)s8 + 1.0f);
        }
        v[k] = s8;
        sum += s8;
    }
    sdata[tid] = sum;
    __syncthreads();
    for (int off = 1; off < SCAN_BLOCK; off <<= 1) {
        int t = (tid >= off) ? sdata[tid - off] : 0;
        __syncthreads();
        sdata[tid] += t;
        __syncthreads();
    }
    if (tid == SCAN_BLOCK - 1) blockSums[blockIdx.x] = sdata[SCAN_BLOCK - 1];
    int run = (tid == 0) ? 0 : sdata[tid - 1];
    #pragma unroll
    for (int k = 0; k < SCAN_ITEMS; ++k) {
        int idx = base + tid * SCAN_ITEMS + k;
        if (idx < n) out[idx] = run;
        run += v[k];
    }
}

__global__ __launch_bounds__(SCAN_BLOCK)
void scan_sums_kernel(int* __restrict__ blockSums, int nB) {
    __shared__ int sdata[SCAN_BLOCK];
    int tid = threadIdx.x;
    sdata[tid] = (tid < nB) ? blockSums[tid] : 0;
    __syncthreads();
    for (int off = 1; off < SCAN_BLOCK; off <<= 1) {
        int t = (tid >= off) ? sdata[tid - off] : 0;
        __syncthreads();
        sdata[tid] += t;
        __syncthreads();
    }
    int excl = (tid == 0) ? 0 : sdata[tid - 1];
    if (tid < nB) blockSums[tid] = excl;
}

// finalize rowptr and emit rp8[c][node] = rowptr[node] + prefix_c(deg8[.][node])
__global__ __launch_bounds__(SCAN_BLOCK)
void scan_add_rp8_kernel(int* __restrict__ rowptr, const int* __restrict__ blockSums,
                         const int* __restrict__ deg8, int* __restrict__ rp8,
                         int n, int E) {
    int base = blockIdx.x * (SCAN_BLOCK * SCAN_ITEMS);
    int add = blockSums[blockIdx.x];
    #pragma unroll
    for (int k = 0; k < SCAN_ITEMS; ++k) {
        int idx = base + threadIdx.x * SCAN_ITEMS + k;
        if (idx < n) {
            int val = rowptr[idx] + add;
            rowptr[idx] = val;
            int run = val;
            #pragma unroll
            for (int c = 0; c < 8; ++c) {
                rp8[(size_t)c * n + idx] = run;
                run += deg8[(size_t)c * n + idx];
            }
        }
    }
    if (blockIdx.x == 0 && threadIdx.x == 0) rowptr[n] = E;
}

// ================= gather kernels =================
// out_i = relu(di * (di*h_i + sum_s dis[s]*h_s) + b).

// F=128, VEC=2: one wave per node, scalarized row base, depth-4 pipeline.
__global__ __launch_bounds__(THREADS)
void gather_bf16_128_kernel(const unsigned short* __restrict__ g, const int* __restrict__ col,
                            const int* __restrict__ rowptr, const float* __restrict__ dis,
                            const float* __restrict__ bias, float* __restrict__ out, int N) {
    constexpr int F = 128;
    int wid = (int)((blockIdx.x * (long long)blockDim.x + threadIdx.x) >> 6);
    wid = __builtin_amdgcn_readfirstlane(wid);
    const int lane = threadIdx.x & 63;
    if (wid >= N) return;
    const float di = dis[wid];
    const int loff = lane * 2;

    float acc0 = 0.0f, acc1 = 0.0f;

    auto loadrow = [&](int s) -> unsigned {
        return *(const unsigned*)(g + (size_t)s * F + loff);
    };
    auto addconv = [&](unsigned u, float w) {
        acc0 += w * bfu2f(u & 0xFFFFu);
        acc1 += w * __builtin_bit_cast(float, u & 0xFFFF0000u);
    };

    addconv(loadrow(wid), di);

    int start = __builtin_amdgcn_readfirstlane(rowptr[wid]);
    int end   = __builtin_amdgcn_readfirstlane(rowptr[wid + 1]);
    const int* c = col + start;
    int rem = end - start;

    if (rem >= 4) {
        int s0 = __builtin_amdgcn_readfirstlane(c[0]);
        int s1 = __builtin_amdgcn_readfirstlane(c[1]);
        int s2 = __builtin_amdgcn_readfirstlane(c[2]);
        int s3 = __builtin_amdgcn_readfirstlane(c[3]);
        float w0 = dis[s0], w1 = dis[s1], w2 = dis[s2], w3 = dis[s3];
        unsigned u0 = loadrow(s0), u1 = loadrow(s1), u2 = loadrow(s2), u3 = loadrow(s3);
        c += 4; rem -= 4;
        while (rem >= 4) {
            int t0 = __builtin_amdgcn_readfirstlane(c[0]);
            int t1 = __builtin_amdgcn_readfirstlane(c[1]);
            int t2 = __builtin_amdgcn_readfirstlane(c[2]);
            int t3 = __builtin_amdgcn_readfirstlane(c[3]);
            float x0 = dis[t0], x1 = dis[t1], x2 = dis[t2], x3 = dis[t3];
            unsigned v0 = loadrow(t0), v1 = loadrow(t1), v2 = loadrow(t2), v3 = loadrow(t3);
            addconv(u0, w0); addconv(u1, w1); addconv(u2, w2); addconv(u3, w3);
            u0 = v0; u1 = v1; u2 = v2; u3 = v3;
            w0 = x0; w1 = x1; w2 = x2; w3 = x3;
            c += 4; rem -= 4;
        }
        addconv(u0, w0); addconv(u1, w1); addconv(u2, w2); addconv(u3, w3);
    }
    while (rem > 0) {
        int s = __builtin_amdgcn_readfirstlane(c[0]);
        addconv(loadrow(s), dis[s]);
        ++c; --rem;
    }

    float* orow = out + (size_t)wid * F + loff;
    float v0 = di * acc0 + bias[loff];
    float v1 = di * acc1 + bias[loff + 1];
    *(float2*)orow = make_float2(fmaxf(v0, 0.0f), fmaxf(v1, 0.0f));
}

// F=64 pairwise: wave halves process alternating edges; 32 lanes x dword per row;
// shfl_xor(32) fold; depth-4 pipeline per half (8 rows in flight per wave).
__global__ __launch_bounds__(THREADS)
void gather_pair64_kernel(const unsigned short* __restrict__ g, const int* __restrict__ col,
                          const int* __restrict__ rowptr, const float* __restrict__ dis,
                          const float* __restrict__ bias, float* __restrict__ out, int N) {
    int wid = (int)((blockIdx.x * (long long)blockDim.x + threadIdx.x) >> 6);
    if (wid >= N) return;
    const int lane = threadIdx.x & 63;
    const int half = lane >> 5;
    const int cc = lane & 31;          // dword index into the 64-elem row
    const float di = dis[wid];

    float acc0 = 0.0f, acc1 = 0.0f;

    auto loadrow = [&](int s) -> unsigned {
        return *(const unsigned*)(g + (size_t)s * 64 + cc * 2);
    };
    auto addconv = [&](unsigned u, float w) {
        acc0 += w * bfu2f(u & 0xFFFFu);
        acc1 += w * __builtin_bit_cast(float, u & 0xFFFF0000u);
    };

    // self row: half 0 carries weight di, half 1 weight 0
    addconv(loadrow(wid), half ? 0.0f : di);

    int start = rowptr[wid], end = rowptr[wid + 1];
    int j = start + half;
    int cnt = (j < end) ? ((end - j + 1) >> 1) : 0;

    if (cnt >= 4) {
        int s0 = col[j], s1 = col[j + 2], s2 = col[j + 4], s3 = col[j + 6];
        float w0 = dis[s0], w1 = dis[s1], w2 = dis[s2], w3 = dis[s3];
        unsigned u0 = loadrow(s0), u1 = loadrow(s1), u2 = loadrow(s2), u3 = loadrow(s3);
        j += 8; cnt -= 4;
        while (cnt >= 4) {
            int t0 = col[j], t1 = col[j + 2], t2 = col[j + 4], t3 = col[j + 6];
            float x0 = dis[t0], x1 = dis[t1], x2 = dis[t2], x3 = dis[t3];
            unsigned v0 = loadrow(t0), v1 = loadrow(t1), v2 = loadrow(t2), v3 = loadrow(t3);
            addconv(u0, w0); addconv(u1, w1); addconv(u2, w2); addconv(u3, w3);
            u0 = v0; u1 = v1; u2 = v2; u3 = v3;
            w0 = x0; w1 = x1; w2 = x2; w3 = x3;
            j += 8; cnt -= 4;
        }
        addconv(u0, w0); addconv(u1, w1); addconv(u2, w2); addconv(u3, w3);
    }
    while (cnt > 0) {
        int s = col[j];
        addconv(loadrow(s), dis[s]);
        j += 2; --cnt;
    }

    acc0 += __shfl_xor(acc0, 32);
    acc1 += __shfl_xor(acc1, 32);

    if (half == 0) {
        float v0 = fmaxf(di * acc0 + bias[cc * 2 + 0], 0.0f);
        float v1 = fmaxf(di * acc1 + bias[cc * 2 + 1], 0.0f);
        *(float2*)(out + (size_t)wid * 64 + cc * 2) = make_float2(v0, v1);
    }
}

// ================= fallback fp32 GEMM + atomic path (round-0, verified) =================

#define BM 64
#define BN 64
#define BK 16

__global__ __launch_bounds__(THREADS)
void sgemm_kernel(const float* __restrict__ A, const float* __restrict__ B,
                  float* __restrict__ C, int M, int N, int K) {
    __shared__ float As[BK][BM + 1];
    __shared__ float Bs[BK][BN + 1];

    const int tid = threadIdx.x;
    const int tr = tid / 16;
    const int tc = tid % 16;
    const int rowBase = blockIdx.y * BM;
    const int colBase = blockIdx.x * BN;

    float acc[4][4] = {};

    for (int k0 = 0; k0 < K; k0 += BK) {
        #pragma unroll
        for (int i = tid; i < BM * BK; i += THREADS) {
            int r = i / BK, c = i % BK;
            int gr = rowBase + r;
            As[c][r] = (gr < M) ? A[(size_t)gr * K + k0 + c] : 0.0f;
        }
        #pragma unroll
        for (int i = tid; i < BK * BN; i += THREADS) {
            int r = i / BN, c = i % BN;
            Bs[r][c] = B[(size_t)(k0 + r) * N + colBase + c];
        }
        __syncthreads();

        #pragma unroll
        for (int k = 0; k < BK; ++k) {
            float a[4], b[4];
            #pragma unroll
            for (int m = 0; m < 4; ++m) a[m] = As[k][tr * 4 + m];
            #pragma unroll
            for (int n = 0; n < 4; ++n) b[n] = Bs[k][tc * 4 + n];
            #pragma unroll
            for (int m = 0; m < 4; ++m)
                #pragma unroll
                for (int n = 0; n < 4; ++n)
                    acc[m][n] += a[m] * b[n];
        }
        __syncthreads();
    }

    #pragma unroll
    for (int m = 0; m < 4; ++m) {
        int gr = rowBase + tr * 4 + m;
        if (gr >= M) continue;
        #pragma unroll
        for (int n = 0; n < 4; ++n) {
            C[(size_t)gr * N + colBase + tc * 4 + n] = acc[m][n];
        }
    }
}

__global__ __launch_bounds__(THREADS)
void init_agg_kernel(const float* __restrict__ h, const float* __restrict__ dis,
                     float* __restrict__ agg, int N, int F) {
    int i = blockIdx.x * blockDim.x + threadIdx.x;
    int total = N * (F / 4);
    if (i >= total) return;
    int node = i / (F / 4);
    float d = dis[node];
    float w = d * d;
    float4 v = ((const float4*)h)[i];
    v.x *= w; v.y *= w; v.z *= w; v.w *= w;
    ((float4*)agg)[i] = v;
}

__global__ __launch_bounds__(THREADS)
void edge_scatter_kernel(const float* __restrict__ h, const int* __restrict__ src,
                         const int* __restrict__ dst, const float* __restrict__ dis,
                         float* __restrict__ agg, int E, int F) {
    int lanesPerEdge = F / 4;
    int tid = blockIdx.x * blockDim.x + threadIdx.x;
    int e = tid / lanesPerEdge;
    int c = tid % lanesPerEdge;
    if (e >= E) return;
    int s = src[e];
    int d = dst[e];
    float w = dis[s] * dis[d];
    float4 hv = ((const float4*)(h + (size_t)s * F))[c];
    float* ap = agg + (size_t)d * F + (size_t)c * 4;
    atomicAdd(ap + 0, hv.x * w);
    atomicAdd(ap + 1, hv.y * w);
    atomicAdd(ap + 2, hv.z * w);
    atomicAdd(ap + 3, hv.w * w);
}

__global__ __launch_bounds__(THREADS)
void finalize_kernel(const float* __restrict__ agg, const float* __restrict__ b,
                     float* __restrict__ out, int N, int F) {
    int i = blockIdx.x * blockDim.x + threadIdx.x;
    int total = N * (F / 4);
    if (i >= total) return;
    int c4 = i % (F / 4);
    float4 bv = ((const float4*)b)[c4];
    float4 v = ((const float4*)agg)[i];
    v.x = fmaxf(v.x + bv.x, 0.0f);
    v.y = fmaxf(v.y + bv.y, 0.0f);
    v.z = fmaxf(v.z + bv.z, 0.0f);
    v.w = fmaxf(v.w + bv.w, 0.0f);
    ((float4*)out)[i] = v;
}

__global__ __launch_bounds__(THREADS)
void fdeg_kernel(const int* __restrict__ dst, float* __restrict__ deg, int E) {
    int i = blockIdx.x * blockDim.x + threadIdx.x;
    if (i < E) atomicAdd(&deg[dst[i]], 1.0f);
}

__global__ __launch_bounds__(THREADS)
void fdis_kernel(float* __restrict__ deg, int N) {
    int i = blockIdx.x * blockDim.x + threadIdx.x;
    if (i < N) deg[i] = rsqrtf(deg[i] + 1.0f);
}

// ================= launch =================

extern "C" void kernel_launch(void* const* d_in, const int* in_sizes, int n_in,
                              void* d_out, int out_size, void* d_ws, size_t ws_size,
                              hipStream_t stream) {
    const float* x  = (const float*)d_in[0];
    const int*   ei = (const int*)d_in[1];
    const float* W1 = (const float*)d_in[2];
    const float* b1 = (const float*)d_in[3];
    const float* W2 = (const float*)d_in[4];
    const float* b2 = (const float*)d_in[5];

    const int E    = in_sizes[1] / 2;
    const int hid  = in_sizes[3];            // 128
    const int outc = in_sizes[5];            // 64
    const int inc  = in_sizes[2] / hid;      // 256
    const int N    = in_sizes[0] / inc;      // 100000

    const int* src = ei;
    const int* dst = ei + E;
    float* out = (float*)d_out;
    char* ws = (char*)d_ws;

    auto al = [](size_t v) { return (v + 255) & ~(size_t)255; };
    size_t o_dis  = 0;
    size_t o_deg8 = al(o_dis + (size_t)N * 4);
    size_t o_rp   = al(o_deg8 + (size_t)N * 32);
    size_t o_rp8  = al(o_rp + ((size_t)N + 1) * 4);
    size_t o_bs   = al(o_rp8 + (size_t)N * 32);
    size_t o_col  = al(o_bs + 4096);
    size_t o_rank = al(o_col + (size_t)E * 4);
    size_t o_bf1  = al(o_rank + (size_t)E * 4);
    size_t o_bf2  = al(o_bf1 + 131072);                // 8*8*1024 shorts
    size_t o_G    = al(o_bf2 + 32768);                 // 4*4*1024 shorts
    size_t o_B    = al(o_G + (size_t)N * hid * 2);     // h rows (bf16)
    size_t need   = o_B + (size_t)N * hid * 4;         // out1 (fp32)

    if (ws_size >= need && N <= SCAN_BLOCK * SCAN_BLOCK * SCAN_ITEMS &&
        hid == 128 && outc == 64 && inc == 256 && E < (1 << 28)) {
        // ---------- CSR gather + MFMA path ----------
        float* dis    = (float*)(ws + o_dis);
        int*   deg8   = (int*)(ws + o_deg8);
        int*   rowptr = (int*)(ws + o_rp);
        int*   rp8    = (int*)(ws + o_rp8);
        int*   bsums  = (int*)(ws + o_bs);
        int*   col    = (int*)(ws + o_col);
        int*   rank   = (int*)(ws + o_rank);
        short* bf1    = (short*)(ws + o_bf1);
        short* bf2    = (short*)(ws + o_bf2);
        unsigned short* gbuf = (unsigned short*)(ws + o_G);  // h1 bf16 (N*128), later h2 (N*64)
        float* out1   = (float*)(ws + o_B);     // fp32 layer-1 output

        const int nbZero  = cdiv((long long)N * 8, 4 * THREADS);
        const int nbHist  = cdiv(E, THREADS * HIST_ILP);
        const int nbGemm1 = cdiv(N, 128);
        const int nbGemmA = (nbGemm1 * 3) / 5;
        const int nbGemmB = nbGemm1 - nbGemmA;
        const int nbFill  = cdiv(E, 4 * THREADS);

        // K0: zero deg8 || weight fragments
        zero_bfrag_kernel<<<nbZero + 20, THREADS, 0, stream>>>(deg8, N * 8, W1, bf1, W2, bf2, nbZero);

        // K1: hist8 || gemm1 part A
        hist_gemmA_kernel<<<nbHist + nbGemmA, THREADS, 0, stream>>>(
            dst, deg8, rank, E, N, x, bf1, gbuf, N, nbHist, nbGemmA);

        // rowptr = exclusive_scan(sum deg8); dis fused; rp8 emitted in scan_add
        int nB = cdiv(N, SCAN_BLOCK * SCAN_ITEMS);
        scan_block_kernel<<<nB, SCAN_BLOCK, 0, stream>>>(deg8, rowptr, bsums, dis, N);
        scan_sums_kernel<<<1, SCAN_BLOCK, 0, stream>>>(bsums, nB);
        scan_add_rp8_kernel<<<nB, SCAN_BLOCK, 0, stream>>>(rowptr, bsums, deg8, rp8, N, E);

        // K2: fill || gemm1 part B
        fill_gemmB_kernel<<<nbFill + nbGemmB, THREADS, 0, stream>>>(
            src, dst, rank, rp8, col, E, N, x, bf1, gbuf, N, nbGemmA, nbFill, nbGemmB);

        // ---- layer 1 gather ----
        gather_bf16_128_kernel<<<cdiv((long long)N * 64, THREADS), THREADS, 0, stream>>>(
            gbuf, col, rowptr, dis, b1, out1, N);

        // ---- layer 2 ----
        mfma_gemm_bf16out_kernel<4, 4><<<cdiv(N, 128), THREADS, 0, stream>>>(out1, bf2, gbuf, N);
        gather_pair64_kernel<<<cdiv((long long)N * 64, THREADS), THREADS, 0, stream>>>(
            gbuf, col, rowptr, dis, b2, out, N);
        return;
    }

    // ---------- fallback: round-0 atomic path ----------
    float* dis = (float*)ws;
    size_t off1 = ((size_t)N * 4 + 255) & ~(size_t)255;
    float* h1 = (float*)(ws + off1);
    size_t off2 = off1 + ((((size_t)N * hid * 4) + 255) & ~(size_t)255);
    float* agg1 = (float*)(ws + off2);
    float* h2   = agg1;
    float* agg2 = agg1 + (size_t)N * outc;

    hipMemsetAsync(dis, 0, (size_t)N * 4, stream);
    fdeg_kernel<<<cdiv(E, THREADS), THREADS, 0, stream>>>(dst, dis, E);
    fdis_kernel<<<cdiv(N, THREADS), THREADS, 0, stream>>>(dis, N);

    {
        dim3 grid(hid / BN, cdiv(N, BM));
        sgemm_kernel<<<grid, THREADS, 0, stream>>>(x, W1, h1, N, hid, inc);
    }
    init_agg_kernel<<<cdiv((long long)N * hid / 4, THREADS), THREADS, 0, stream>>>(h1, dis, agg1, N, hid);
    edge_scatter_kernel<<<cdiv((long long)E * (hid / 4), THREADS), THREADS, 0, stream>>>(
        h1, src, dst, dis, agg1, E, hid);
    finalize_kernel<<<cdiv((long long)N * hid / 4, THREADS), THREADS, 0, stream>>>(agg1, b1, h1, N, hid);

    {
        dim3 grid(outc / BN, cdiv(N, BM));
        sgemm_kernel<<<grid, THREADS, 0, stream>>>(h1, W2, h2, N, outc, hid);
    }
    init_agg_kernel<<<cdiv((long long)N * outc / 4, THREADS), THREADS, 0, stream>>>(h2, dis, agg2, N, outc);
    edge_scatter_kernel<<<cdiv((long long)E * (outc / 4), THREADS), THREADS, 0, stream>>>(
        h2, src, dst, dis, agg2, E, outc);
    finalize_kernel<<<cdiv((long long)N * outc / 4, THREADS), THREADS, 0, stream>>>(agg2, b2, out, N, outc);
}

// Round 11
// 281.996 us; speedup vs baseline: 1.0376x; 1.0289x over previous
//
#include <hip/hip_runtime.h>
#include <math.h>

#define THREADS 256
#define HIST_ILP 8
#define EPB_SHIFT 11   // edges per hist block = THREADS*HIST_ILP = 2048

static inline int cdiv(long long a, long long b) { return (int)((a + b - 1) / b); }

typedef __attribute__((ext_vector_type(8))) short bf16x8;
typedef __attribute__((ext_vector_type(4))) float f32x4;

__device__ inline unsigned f2bf_rne_u(float f) {
    unsigned u = __builtin_bit_cast(unsigned, f);
    return (u + 0x7FFFu + ((u >> 16) & 1u)) >> 16;
}
__device__ inline float bfu2f(unsigned h) {
    unsigned u = h << 16;
    return __builtin_bit_cast(float, u);
}

// ================= device bodies =================

// one 64-lane unit builds one (hi,lo) W-fragment pair
__device__ __forceinline__ void bfrag_unit(const float* __restrict__ W, short* __restrict__ frag,
                                           int NCT, int ctks, int lane) {
    int Nn = NCT * 16;
    int ct = ctks % NCT;
    int ks = ctks / NCT;
    int colc = ct * 16 + (lane & 15);
    int kbase = ks * 32 + (lane >> 4) * 8;
    short* base = frag + (size_t)ctks * 1024 + lane * 8;
    #pragma unroll
    for (int j = 0; j < 8; ++j) {
        float v = W[(size_t)(kbase + j) * Nn + colc];
        unsigned h = f2bf_rne_u(v);
        base[j] = (short)h;
        base[512 + j] = (short)f2bf_rne_u(v - bfu2f(h));
    }
}

// shared-deg histogram + rank, 8 edges/thread
__device__ __forceinline__ void hist_body8(const int* __restrict__ dst, int* __restrict__ deg,
                                           int* __restrict__ rank, int E, int hb) {
    int base = (hb << EPB_SHIFT) + (int)threadIdx.x * HIST_ILP;
    if (base + HIST_ILP - 1 < E) {
        int4 d0 = *(const int4*)(dst + base);
        int4 d1 = *(const int4*)(dst + base + 4);
        int4 r0, r1;
        r0.x = atomicAdd(&deg[d0.x], 1);
        r0.y = atomicAdd(&deg[d0.y], 1);
        r0.z = atomicAdd(&deg[d0.z], 1);
        r0.w = atomicAdd(&deg[d0.w], 1);
        r1.x = atomicAdd(&deg[d1.x], 1);
        r1.y = atomicAdd(&deg[d1.y], 1);
        r1.z = atomicAdd(&deg[d1.z], 1);
        r1.w = atomicAdd(&deg[d1.w], 1);
        *(int4*)(rank + base) = r0;
        *(int4*)(rank + base + 4) = r1;
    } else {
        for (int e = base; e < E; ++e) rank[e] = atomicAdd(&deg[dst[e]], 1);
    }
}

// CSR fill, atomic-free, 4 edges/thread
__device__ __forceinline__ void fill_body(const int* __restrict__ src, const int* __restrict__ dst,
                                          const int* __restrict__ rank, const int* __restrict__ rowptr,
                                          int* __restrict__ col, int E, int blk) {
    int base = (blk * THREADS + (int)threadIdx.x) * 4;
    if (base + 3 < E) {
        int4 d = *(const int4*)(dst + base);
        int4 r = *(const int4*)(rank + base);
        int4 s = *(const int4*)(src + base);
        col[rowptr[d.x] + r.x] = s.x;
        col[rowptr[d.y] + r.y] = s.y;
        col[rowptr[d.z] + r.z] = s.z;
        col[rowptr[d.w] + r.w] = s.w;
    } else {
        for (int e = base; e < E; ++e)
            col[rowptr[dst[e]] + rank[e]] = src[e];
    }
}

// split-bf16 MFMA GEMM body with depth-1 A-prefetch: writes H = bf16(A @ W).
template<int NCT, int KS>
__device__ __forceinline__ void gemm_body(const float* __restrict__ A, const short* __restrict__ Bfrag,
                                          unsigned short* __restrict__ H, int M, int blk) {
    constexpr int K = KS * 32;
    constexpr int Nn = NCT * 16;
    const int lane = threadIdx.x & 63;
    const int wave = threadIdx.x >> 6;
    const int rowBase = blk * 128 + wave * 32;
    const int kgrp = (lane >> 4) * 8;

    const float* ap0;
    const float* ap1;
    {
        int r0 = rowBase + (lane & 15);      if (r0 >= M) r0 = M - 1;
        int r1 = rowBase + (lane & 15) + 16; if (r1 >= M) r1 = M - 1;
        ap0 = A + (size_t)r0 * K + kgrp;
        ap1 = A + (size_t)r1 * K + kgrp;
    }

    f32x4 acc[2][NCT] = {};

    float4 c00 = *(const float4*)(ap0);
    float4 c01 = *(const float4*)(ap0 + 4);
    float4 c10 = *(const float4*)(ap1);
    float4 c11 = *(const float4*)(ap1 + 4);

    for (int ks = 0; ks < KS; ++ks) {
        float4 n00, n01, n10, n11;
        if (ks + 1 < KS) {
            const float* p0 = ap0 + (size_t)(ks + 1) * 32;
            const float* p1 = ap1 + (size_t)(ks + 1) * 32;
            n00 = *(const float4*)(p0);
            n01 = *(const float4*)(p0 + 4);
            n10 = *(const float4*)(p1);
            n11 = *(const float4*)(p1 + 4);
        }
        bf16x8 ahi[2], alo[2];
        {
            float av0[8] = {c00.x, c00.y, c00.z, c00.w, c01.x, c01.y, c01.z, c01.w};
            float av1[8] = {c10.x, c10.y, c10.z, c10.w, c11.x, c11.y, c11.z, c11.w};
            #pragma unroll
            for (int j = 0; j < 8; ++j) {
                unsigned h0 = f2bf_rne_u(av0[j]);
                ahi[0][j] = (short)h0;
                alo[0][j] = (short)f2bf_rne_u(av0[j] - bfu2f(h0));
                unsigned h1 = f2bf_rne_u(av1[j]);
                ahi[1][j] = (short)h1;
                alo[1][j] = (short)f2bf_rne_u(av1[j] - bfu2f(h1));
            }
        }
        __builtin_amdgcn_s_setprio(1);
        #pragma unroll
        for (int ct = 0; ct < NCT; ++ct) {
            const short* bp = Bfrag + (size_t)(ks * NCT + ct) * 1024 + lane * 8;
            bf16x8 bhi = *(const bf16x8*)bp;
            bf16x8 blo = *(const bf16x8*)(bp + 512);
            #pragma unroll
            for (int t = 0; t < 2; ++t) {
                acc[t][ct] = __builtin_amdgcn_mfma_f32_16x16x32_bf16(ahi[t], bhi, acc[t][ct], 0, 0, 0);
                acc[t][ct] = __builtin_amdgcn_mfma_f32_16x16x32_bf16(ahi[t], blo, acc[t][ct], 0, 0, 0);
                acc[t][ct] = __builtin_amdgcn_mfma_f32_16x16x32_bf16(alo[t], bhi, acc[t][ct], 0, 0, 0);
            }
        }
        __builtin_amdgcn_s_setprio(0);
        c00 = n00; c01 = n01; c10 = n10; c11 = n11;
    }

    const int drow0 = rowBase + (lane >> 4) * 4;
    #pragma unroll
    for (int t = 0; t < 2; ++t) {
        #pragma unroll
        for (int r = 0; r < 4; ++r) {
            int row = drow0 + t * 16 + r;
            if (row < M) {
                unsigned short* hp = H + (size_t)row * Nn + (lane & 15);
                #pragma unroll
                for (int ct = 0; ct < NCT; ++ct)
                    hp[ct * 16] = (unsigned short)f2bf_rne_u(acc[t][ct][r]);
            }
        }
    }
}

// ================= kernels =================

// K0: [zero deg | bfrag]
__global__ __launch_bounds__(THREADS)
void zero_bfrag_kernel(int* __restrict__ deg, int N,
                       const float* __restrict__ W1, short* __restrict__ bf1,
                       const float* __restrict__ W2, short* __restrict__ bf2, int nbZero) {
    int b = (int)blockIdx.x;
    if (b < nbZero) {
        int base = (b * THREADS + (int)threadIdx.x) * 4;
        if (base + 3 < N) {
            *(int4*)(deg + base) = make_int4(0, 0, 0, 0);
        } else {
            for (int i = base; i < N; ++i) deg[i] = 0;
        }
    } else {
        int u = (b - nbZero) * 4 + ((int)threadIdx.x >> 6);
        int lane = threadIdx.x & 63;
        if (u < 64) bfrag_unit(W1, bf1, 8, u, lane);
        else if (u < 80) bfrag_unit(W2, bf2, 4, u - 64, lane);
    }
}

// K1: [hist || gemm1 part A] Bresenham-interleaved
__global__ __launch_bounds__(THREADS)
void hist_gemmA_kernel(const int* __restrict__ dst, int* __restrict__ deg,
                       int* __restrict__ rank, int E,
                       const float* __restrict__ A, const short* __restrict__ Bfrag,
                       unsigned short* __restrict__ H, int M,
                       int nbHist, int nbGemm) {
    int b = (int)blockIdx.x;
    int total = nbHist + nbGemm;
    long long t = (long long)b * nbGemm;
    int gBefore = (int)(t / total);
    bool isG = (((long long)(b + 1) * nbGemm) / total) > gBefore;
    if (isG) gemm_body<8, 8>(A, Bfrag, H, M, gBefore);
    else     hist_body8(dst, deg, rank, E, b - gBefore);
}

// K2: [fill || gemm1 part B] Bresenham-interleaved
__global__ __launch_bounds__(THREADS)
void fill_gemmB_kernel(const int* __restrict__ src, const int* __restrict__ dst,
                       const int* __restrict__ rank, const int* __restrict__ rowptr,
                       int* __restrict__ col, int E,
                       const float* __restrict__ A, const short* __restrict__ Bfrag,
                       unsigned short* __restrict__ H, int M, int gemmOff,
                       int nbFill, int nbGemm) {
    int b = (int)blockIdx.x;
    int total = nbFill + nbGemm;
    long long t = (long long)b * nbGemm;
    int gBefore = (int)(t / total);
    bool isG = (((long long)(b + 1) * nbGemm) / total) > gBefore;
    if (isG) gemm_body<8, 8>(A, Bfrag, H, M, gemmOff + gBefore);
    else     fill_body(src, dst, rank, rowptr, col, E, b - gBefore);
}

// standalone GEMM (layer 2)
template<int NCT, int KS>
__global__ __launch_bounds__(THREADS)
void mfma_gemm_bf16out_kernel(const float* __restrict__ A, const short* __restrict__ Bfrag,
                              unsigned short* __restrict__ H, int M) {
    gemm_body<NCT, KS>(A, Bfrag, H, M, (int)blockIdx.x);
}

// ================= exclusive scan, fused dis =================

#define SCAN_BLOCK 256
#define SCAN_ITEMS 4   // 1024 elements per block

__global__ __launch_bounds__(SCAN_BLOCK)
void scan_block_kernel(const int* __restrict__ in, int* __restrict__ out,
                       int* __restrict__ blockSums, float* __restrict__ dis, int n) {
    __shared__ int sdata[SCAN_BLOCK];
    int base = blockIdx.x * (SCAN_BLOCK * SCAN_ITEMS);
    int tid = threadIdx.x;
    int v[SCAN_ITEMS];
    int sum = 0;
    #pragma unroll
    for (int k = 0; k < SCAN_ITEMS; ++k) {
        int idx = base + tid * SCAN_ITEMS + k;
        v[k] = (idx < n) ? in[idx] : 0;
        if (idx < n) dis[idx] = rsqrtf((float)v[k] + 1.0f);
        sum += v[k];
    }
    sdata[tid] = sum;
    __syncthreads();
    for (int off = 1; off < SCAN_BLOCK; off <<= 1) {
        int t = (tid >= off) ? sdata[tid - off] : 0;
        __syncthreads();
        sdata[tid] += t;
        __syncthreads();
    }
    if (tid == SCAN_BLOCK - 1) blockSums[blockIdx.x] = sdata[SCAN_BLOCK - 1];
    int run = (tid == 0) ? 0 : sdata[tid - 1];
    #pragma unroll
    for (int k = 0; k < SCAN_ITEMS; ++k) {
        int idx = base + tid * SCAN_ITEMS + k;
        if (idx < n) out[idx] = run;
        run += v[k];
    }
}

__global__ __launch_bounds__(SCAN_BLOCK)
void scan_sums_kernel(int* __restrict__ blockSums, int nB) {
    __shared__ int sdata[SCAN_BLOCK];
    int tid = threadIdx.x;
    sdata[tid] = (tid < nB) ? blockSums[tid] : 0;
    __syncthreads();
    for (int off = 1; off < SCAN_BLOCK; off <<= 1) {
        int t = (tid >= off) ? sdata[tid - off] : 0;
        __syncthreads();
        sdata[tid] += t;
        __syncthreads();
    }
    int excl = (tid == 0) ? 0 : sdata[tid - 1];
    if (tid < nB) blockSums[tid] = excl;
}

__global__ __launch_bounds__(SCAN_BLOCK)
void scan_add_kernel(int* __restrict__ out, const int* __restrict__ blockSums,
                     int n, int E) {
    int base = blockIdx.x * (SCAN_BLOCK * SCAN_ITEMS);
    int add = blockSums[blockIdx.x];
    #pragma unroll
    for (int k = 0; k < SCAN_ITEMS; ++k) {
        int idx = base + threadIdx.x * SCAN_ITEMS + k;
        if (idx < n) out[idx] += add;
    }
    if (blockIdx.x == 0 && threadIdx.x == 0) out[n] = E;
}

// ================= pairwise half-wave gathers =================
// out_i = relu(di * (di*h_i + sum_s dis[s]*h_s) + b). Halves process alternating
// edges; shfl_xor(32) fold; depth-4 pipeline per half (8 rows in flight/wave).

// F=128: 32 lanes x 8B (4 bf16) per row.
__global__ __launch_bounds__(THREADS)
void gather_pair128_kernel(const unsigned short* __restrict__ g, const int* __restrict__ col,
                           const int* __restrict__ rowptr, const float* __restrict__ dis,
                           const float* __restrict__ bias, float* __restrict__ out, int N) {
    int wid = (int)((blockIdx.x * (long long)blockDim.x + threadIdx.x) >> 6);
    if (wid >= N) return;
    const int lane = threadIdx.x & 63;
    const int half = lane >> 5;
    const int cc = lane & 31;          // 4 bf16 per lane
    const float di = dis[wid];

    float a0 = 0, a1 = 0, a2 = 0, a3 = 0;

    auto loadrow = [&](int s) -> uint2 {
        return *(const uint2*)(g + (size_t)s * 128 + cc * 4);
    };
    auto addconv = [&](uint2 u, float w) {
        a0 += w * bfu2f(u.x & 0xFFFFu);
        a1 += w * __builtin_bit_cast(float, u.x & 0xFFFF0000u);
        a2 += w * bfu2f(u.y & 0xFFFFu);
        a3 += w * __builtin_bit_cast(float, u.y & 0xFFFF0000u);
    };

    if (half == 0) addconv(loadrow(wid), di);   // self row, half 0 only

    int start = rowptr[wid], end = rowptr[wid + 1];
    int j = start + half;
    int cnt = (j < end) ? ((end - j + 1) >> 1) : 0;

    if (cnt >= 4) {
        int s0 = col[j], s1 = col[j + 2], s2 = col[j + 4], s3 = col[j + 6];
        float w0 = dis[s0], w1 = dis[s1], w2 = dis[s2], w3 = dis[s3];
        uint2 u0 = loadrow(s0), u1 = loadrow(s1), u2 = loadrow(s2), u3 = loadrow(s3);
        j += 8; cnt -= 4;
        while (cnt >= 4) {
            int t0 = col[j], t1 = col[j + 2], t2 = col[j + 4], t3 = col[j + 6];
            float x0 = dis[t0], x1 = dis[t1], x2 = dis[t2], x3 = dis[t3];
            uint2 v0 = loadrow(t0), v1 = loadrow(t1), v2 = loadrow(t2), v3 = loadrow(t3);
            addconv(u0, w0); addconv(u1, w1); addconv(u2, w2); addconv(u3, w3);
            u0 = v0; u1 = v1; u2 = v2; u3 = v3;
            w0 = x0; w1 = x1; w2 = x2; w3 = x3;
            j += 8; cnt -= 4;
        }
        addconv(u0, w0); addconv(u1, w1); addconv(u2, w2); addconv(u3, w3);
    }
    while (cnt > 0) {
        int s = col[j];
        addconv(loadrow(s), dis[s]);
        j += 2; --cnt;
    }

    a0 += __shfl_xor(a0, 32);
    a1 += __shfl_xor(a1, 32);
    a2 += __shfl_xor(a2, 32);
    a3 += __shfl_xor(a3, 32);

    if (half == 0) {
        float4 v;
        v.x = fmaxf(di * a0 + bias[cc * 4 + 0], 0.0f);
        v.y = fmaxf(di * a1 + bias[cc * 4 + 1], 0.0f);
        v.z = fmaxf(di * a2 + bias[cc * 4 + 2], 0.0f);
        v.w = fmaxf(di * a3 + bias[cc * 4 + 3], 0.0f);
        *(float4*)(out + (size_t)wid * 128 + cc * 4) = v;
    }
}

// F=64: 32 lanes x 4B (2 bf16) per row.
__global__ __launch_bounds__(THREADS)
void gather_pair64_kernel(const unsigned short* __restrict__ g, const int* __restrict__ col,
                          const int* __restrict__ rowptr, const float* __restrict__ dis,
                          const float* __restrict__ bias, float* __restrict__ out, int N) {
    int wid = (int)((blockIdx.x * (long long)blockDim.x + threadIdx.x) >> 6);
    if (wid >= N) return;
    const int lane = threadIdx.x & 63;
    const int half = lane >> 5;
    const int cc = lane & 31;
    const float di = dis[wid];

    float a0 = 0, a1 = 0;

    auto loadrow = [&](int s) -> unsigned {
        return *(const unsigned*)(g + (size_t)s * 64 + cc * 2);
    };
    auto addconv = [&](unsigned u, float w) {
        a0 += w * bfu2f(u & 0xFFFFu);
        a1 += w * __builtin_bit_cast(float, u & 0xFFFF0000u);
    };

    if (half == 0) addconv(loadrow(wid), di);   // self row, half 0 only

    int start = rowptr[wid], end = rowptr[wid + 1];
    int j = start + half;
    int cnt = (j < end) ? ((end - j + 1) >> 1) : 0;

    if (cnt >= 4) {
        int s0 = col[j], s1 = col[j + 2], s2 = col[j + 4], s3 = col[j + 6];
        float w0 = dis[s0], w1 = dis[s1], w2 = dis[s2], w3 = dis[s3];
        unsigned u0 = loadrow(s0), u1 = loadrow(s1), u2 = loadrow(s2), u3 = loadrow(s3);
        j += 8; cnt -= 4;
        while (cnt >= 4) {
            int t0 = col[j], t1 = col[j + 2], t2 = col[j + 4], t3 = col[j + 6];
            float x0 = dis[t0], x1 = dis[t1], x2 = dis[t2], x3 = dis[t3];
            unsigned v0 = loadrow(t0), v1 = loadrow(t1), v2 = loadrow(t2), v3 = loadrow(t3);
            addconv(u0, w0); addconv(u1, w1); addconv(u2, w2); addconv(u3, w3);
            u0 = v0; u1 = v1; u2 = v2; u3 = v3;
            w0 = x0; w1 = x1; w2 = x2; w3 = x3;
            j += 8; cnt -= 4;
        }
        addconv(u0, w0); addconv(u1, w1); addconv(u2, w2); addconv(u3, w3);
    }
    while (cnt > 0) {
        int s = col[j];
        addconv(loadrow(s), dis[s]);
        j += 2; --cnt;
    }

    a0 += __shfl_xor(a0, 32);
    a1 += __shfl_xor(a1, 32);

    if (half == 0) {
        float v0 = fmaxf(di * a0 + bias[cc * 2 + 0], 0.0f);
        float v1 = fmaxf(di * a1 + bias[cc * 2 + 1], 0.0f);
        *(float2*)(out + (size_t)wid * 64 + cc * 2) = make_float2(v0, v1);
    }
}

// ================= fallback fp32 GEMM + atomic path (round-0, verified) =================

#define BM 64
#define BN 64
#define BK 16

__global__ __launch_bounds__(THREADS)
void sgemm_kernel(const float* __restrict__ A, const float* __restrict__ B,
                  float* __restrict__ C, int M, int N, int K) {
    __shared__ float As[BK][BM + 1];
    __shared__ float Bs[BK][BN + 1];

    const int tid = threadIdx.x;
    const int tr = tid / 16;
    const int tc = tid % 16;
    const int rowBase = blockIdx.y * BM;
    const int colBase = blockIdx.x * BN;

    float acc[4][4] = {};

    for (int k0 = 0; k0 < K; k0 += BK) {
        #pragma unroll
        for (int i = tid; i < BM * BK; i += THREADS) {
            int r = i / BK, c = i % BK;
            int gr = rowBase + r;
            As[c][r] = (gr < M) ? A[(size_t)gr * K + k0 + c] : 0.0f;
        }
        #pragma unroll
        for (int i = tid; i < BK * BN; i += THREADS) {
            int r = i / BN, c = i % BN;
            Bs[r][c] = B[(size_t)(k0 + r) * N + colBase + c];
        }
        __syncthreads();

        #pragma unroll
        for (int k = 0; k < BK; ++k) {
            float a[4], b[4];
            #pragma unroll
            for (int m = 0; m < 4; ++m) a[m] = As[k][tr * 4 + m];
            #pragma unroll
            for (int n = 0; n < 4; ++n) b[n] = Bs[k][tc * 4 + n];
            #pragma unroll
            for (int m = 0; m < 4; ++m)
                #pragma unroll
                for (int n = 0; n < 4; ++n)
                    acc[m][n] += a[m] * b[n];
        }
        __syncthreads();
    }

    #pragma unroll
    for (int m = 0; m < 4; ++m) {
        int gr = rowBase + tr * 4 + m;
        if (gr >= M) continue;
        #pragma unroll
        for (int n = 0; n < 4; ++n) {
            C[(size_t)gr * N + colBase + tc * 4 + n] = acc[m][n];
        }
    }
}

__global__ __launch_bounds__(THREADS)
void init_agg_kernel(const float* __restrict__ h, const float* __restrict__ dis,
                     float* __restrict__ agg, int N, int F) {
    int i = blockIdx.x * blockDim.x + threadIdx.x;
    int total = N * (F / 4);
    if (i >= total) return;
    int node = i / (F / 4);
    float d = dis[node];
    float w = d * d;
    float4 v = ((const float4*)h)[i];
    v.x *= w; v.y *= w; v.z *= w; v.w *= w;
    ((float4*)agg)[i] = v;
}

__global__ __launch_bounds__(THREADS)
void edge_scatter_kernel(const float* __restrict__ h, const int* __restrict__ src,
                         const int* __restrict__ dst, const float* __restrict__ dis,
                         float* __restrict__ agg, int E, int F) {
    int lanesPerEdge = F / 4;
    int tid = blockIdx.x * blockDim.x + threadIdx.x;
    int e = tid / lanesPerEdge;
    int c = tid % lanesPerEdge;
    if (e >= E) return;
    int s = src[e];
    int d = dst[e];
    float w = dis[s] * dis[d];
    float4 hv = ((const float4*)(h + (size_t)s * F))[c];
    float* ap = agg + (size_t)d * F + (size_t)c * 4;
    atomicAdd(ap + 0, hv.x * w);
    atomicAdd(ap + 1, hv.y * w);
    atomicAdd(ap + 2, hv.z * w);
    atomicAdd(ap + 3, hv.w * w);
}

__global__ __launch_bounds__(THREADS)
void finalize_kernel(const float* __restrict__ agg, const float* __restrict__ b,
                     float* __restrict__ out, int N, int F) {
    int i = blockIdx.x * blockDim.x + threadIdx.x;
    int total = N * (F / 4);
    if (i >= total) return;
    int c4 = i % (F / 4);
    float4 bv = ((const float4*)b)[c4];
    float4 v = ((const float4*)agg)[i];
    v.x = fmaxf(v.x + bv.x, 0.0f);
    v.y = fmaxf(v.y + bv.y, 0.0f);
    v.z = fmaxf(v.z + bv.z, 0.0f);
    v.w = fmaxf(v.w + bv.w, 0.0f);
    ((float4*)out)[i] = v;
}

__global__ __launch_bounds__(THREADS)
void fdeg_kernel(const int* __restrict__ dst, float* __restrict__ deg, int E) {
    int i = blockIdx.x * blockDim.x + threadIdx.x;
    if (i < E) atomicAdd(&deg[dst[i]], 1.0f);
}

__global__ __launch_bounds__(THREADS)
void fdis_kernel(float* __restrict__ deg, int N) {
    int i = blockIdx.x * blockDim.x + threadIdx.x;
    if (i < N) deg[i] = rsqrtf(deg[i] + 1.0f);
}

// ================= launch =================

extern "C" void kernel_launch(void* const* d_in, const int* in_sizes, int n_in,
                              void* d_out, int out_size, void* d_ws, size_t ws_size,
                              hipStream_t stream) {
    const float* x  = (const float*)d_in[0];
    const int*   ei = (const int*)d_in[1];
    const float* W1 = (const float*)d_in[2];
    const float* b1 = (const float*)d_in[3];
    const float* W2 = (const float*)d_in[4];
    const float* b2 = (const float*)d_in[5];

    const int E    = in_sizes[1] / 2;
    const int hid  = in_sizes[3];            // 128
    const int outc = in_sizes[5];            // 64
    const int inc  = in_sizes[2] / hid;      // 256
    const int N    = in_sizes[0] / inc;      // 100000

    const int* src = ei;
    const int* dst = ei + E;
    float* out = (float*)d_out;
    char* ws = (char*)d_ws;

    auto al = [](size_t v) { return (v + 255) & ~(size_t)255; };
    size_t o_dis  = 0;
    size_t o_deg  = al(o_dis + (size_t)N * 4);
    size_t o_rp   = al(o_deg + (size_t)N * 4);
    size_t o_bs   = al(o_rp + ((size_t)N + 1) * 4);
    size_t o_col  = al(o_bs + 4096);
    size_t o_rank = al(o_col + (size_t)E * 4);
    size_t o_bf1  = al(o_rank + (size_t)E * 4);
    size_t o_bf2  = al(o_bf1 + 131072);                // 8*8*1024 shorts
    size_t o_G    = al(o_bf2 + 32768);                 // 4*4*1024 shorts
    size_t o_B    = al(o_G + (size_t)N * hid * 2);     // h rows (bf16)
    size_t need   = o_B + (size_t)N * hid * 4;         // out1 (fp32)

    if (ws_size >= need && N <= SCAN_BLOCK * SCAN_BLOCK * SCAN_ITEMS &&
        hid == 128 && outc == 64 && inc == 256) {
        // ---------- CSR gather + MFMA path ----------
        float* dis    = (float*)(ws + o_dis);
        int*   deg    = (int*)(ws + o_deg);
        int*   rowptr = (int*)(ws + o_rp);
        int*   bsums  = (int*)(ws + o_bs);
        int*   col    = (int*)(ws + o_col);
        int*   rank   = (int*)(ws + o_rank);
        short* bf1    = (short*)(ws + o_bf1);
        short* bf2    = (short*)(ws + o_bf2);
        unsigned short* gbuf = (unsigned short*)(ws + o_G);  // h1 bf16 (N*128), later h2 (N*64)
        float* out1   = (float*)(ws + o_B);     // fp32 layer-1 output

        const int nbZero  = cdiv(N, 4 * THREADS);
        const int nbHist  = cdiv(E, THREADS * HIST_ILP);
        const int nbGemm1 = cdiv(N, 128);
        const int nbGemmA = (nbGemm1 * 5) / 9;
        const int nbGemmB = nbGemm1 - nbGemmA;
        const int nbFill  = cdiv(E, 4 * THREADS);

        // K0: zero deg || weight fragments
        zero_bfrag_kernel<<<nbZero + 20, THREADS, 0, stream>>>(deg, N, W1, bf1, W2, bf2, nbZero);

        // K1: hist (shared deg, ILP-8) || gemm1 part A
        hist_gemmA_kernel<<<nbHist + nbGemmA, THREADS, 0, stream>>>(
            dst, deg, rank, E, x, bf1, gbuf, N, nbHist, nbGemmA);

        // rowptr = exclusive_scan(deg); dis fused
        int nB = cdiv(N, SCAN_BLOCK * SCAN_ITEMS);
        scan_block_kernel<<<nB, SCAN_BLOCK, 0, stream>>>(deg, rowptr, bsums, dis, N);
        scan_sums_kernel<<<1, SCAN_BLOCK, 0, stream>>>(bsums, nB);
        scan_add_kernel<<<nB, SCAN_BLOCK, 0, stream>>>(rowptr, bsums, N, E);

        // K2: fill || gemm1 part B
        fill_gemmB_kernel<<<nbFill + nbGemmB, THREADS, 0, stream>>>(
            src, dst, rank, rowptr, col, E, x, bf1, gbuf, N, nbGemmA, nbFill, nbGemmB);

        // ---- layer 1 gather ----
        gather_pair128_kernel<<<cdiv((long long)N * 64, THREADS), THREADS, 0, stream>>>(
            gbuf, col, rowptr, dis, b1, out1, N);

        // ---- layer 2 ----
        mfma_gemm_bf16out_kernel<4, 4><<<cdiv(N, 128), THREADS, 0, stream>>>(out1, bf2, gbuf, N);
        gather_pair64_kernel<<<cdiv((long long)N * 64, THREADS), THREADS, 0, stream>>>(
            gbuf, col, rowptr, dis, b2, out, N);
        return;
    }

    // ---------- fallback: round-0 atomic path ----------
    float* dis = (float*)ws;
    size_t off1 = ((size_t)N * 4 + 255) & ~(size_t)255;
    float* h1 = (float*)(ws + off1);
    size_t off2 = off1 + ((((size_t)N * hid * 4) + 255) & ~(size_t)255);
    float* agg1 = (float*)(ws + off2);
    float* h2   = agg1;
    float* agg2 = agg1 + (size_t)N * outc;

    hipMemsetAsync(dis, 0, (size_t)N * 4, stream);
    fdeg_kernel<<<cdiv(E, THREADS), THREADS, 0, stream>>>(dst, dis, E);
    fdis_kernel<<<cdiv(N, THREADS), THREADS, 0, stream>>>(dis, N);

    {
        dim3 grid(hid / BN, cdiv(N, BM));
        sgemm_kernel<<<grid, THREADS, 0, stream>>>(x, W1, h1, N, hid, inc);
    }
    init_agg_kernel<<<cdiv((long long)N * hid / 4, THREADS), THREADS, 0, stream>>>(h1, dis, agg1, N, hid);
    edge_scatter_kernel<<<cdiv((long long)E * (hid / 4), THREADS), THREADS, 0, stream>>>(
        h1, src, dst, dis, agg1, E, hid);
    finalize_kernel<<<cdiv((long long)N * hid / 4, THREADS), THREADS, 0, stream>>>(agg1, b1, h1, N, hid);

    {
        dim3 grid(outc / BN, cdiv(N, BM));
        sgemm_kernel<<<grid, THREADS, 0, stream>>>(h1, W2, h2, N, outc, hid);
    }
    init_agg_kernel<<<cdiv((long long)N * outc / 4, THREADS), THREADS, 0, stream>>>(h2, dis, agg2, N, outc);
    edge_scatter_kernel<<<cdiv((long long)E * (outc / 4), THREADS), THREADS, 0, stream>>>(
        h2, src, dst, dis, agg2, E, outc);
    finalize_kernel<<<cdiv((long long)N * outc / 4, THREADS), THREADS, 0, stream>>>(agg2, b2, out, N, outc);
}

// Round 12
// 272.283 us; speedup vs baseline: 1.0746x; 1.0357x over previous
//
#include <hip/hip_runtime.h>
#include <math.h>

#define THREADS 256
#define HIST_ILP 8
#define EPB_SHIFT 11   // edges per hist block = THREADS*HIST_ILP = 2048

static inline int cdiv(long long a, long long b) { return (int)((a + b - 1) / b); }

typedef __attribute__((ext_vector_type(8))) short bf16x8;
typedef __attribute__((ext_vector_type(4))) float f32x4;

__device__ inline unsigned f2bf_rne_u(float f) {
    unsigned u = __builtin_bit_cast(unsigned, f);
    return (u + 0x7FFFu + ((u >> 16) & 1u)) >> 16;
}
__device__ inline float bfu2f(unsigned h) {
    unsigned u = h << 16;
    return __builtin_bit_cast(float, u);
}

// ================= device bodies =================

__device__ __forceinline__ void bfrag_unit(const float* __restrict__ W, short* __restrict__ frag,
                                           int NCT, int ctks, int lane) {
    int Nn = NCT * 16;
    int ct = ctks % NCT;
    int ks = ctks / NCT;
    int colc = ct * 16 + (lane & 15);
    int kbase = ks * 32 + (lane >> 4) * 8;
    short* base = frag + (size_t)ctks * 1024 + lane * 8;
    #pragma unroll
    for (int j = 0; j < 8; ++j) {
        float v = W[(size_t)(kbase + j) * Nn + colc];
        unsigned h = f2bf_rne_u(v);
        base[j] = (short)h;
        base[512 + j] = (short)f2bf_rne_u(v - bfu2f(h));
    }
}

// shared-deg histogram + rank, 8 edges/thread
__device__ __forceinline__ void hist_body8(const int* __restrict__ dst, int* __restrict__ deg,
                                           int* __restrict__ rank, int E, int hb) {
    int base = (hb << EPB_SHIFT) + (int)threadIdx.x * HIST_ILP;
    if (base + HIST_ILP - 1 < E) {
        int4 d0 = *(const int4*)(dst + base);
        int4 d1 = *(const int4*)(dst + base + 4);
        int4 r0, r1;
        r0.x = atomicAdd(&deg[d0.x], 1);
        r0.y = atomicAdd(&deg[d0.y], 1);
        r0.z = atomicAdd(&deg[d0.z], 1);
        r0.w = atomicAdd(&deg[d0.w], 1);
        r1.x = atomicAdd(&deg[d1.x], 1);
        r1.y = atomicAdd(&deg[d1.y], 1);
        r1.z = atomicAdd(&deg[d1.z], 1);
        r1.w = atomicAdd(&deg[d1.w], 1);
        *(int4*)(rank + base) = r0;
        *(int4*)(rank + base + 4) = r1;
    } else {
        for (int e = base; e < E; ++e) rank[e] = atomicAdd(&deg[dst[e]], 1);
    }
}

// split-bf16 MFMA GEMM body with depth-1 A-prefetch: writes H = bf16(A @ W).
template<int NCT, int KS>
__device__ __forceinline__ void gemm_body(const float* __restrict__ A, const short* __restrict__ Bfrag,
                                          unsigned short* __restrict__ H, int M, int blk) {
    constexpr int K = KS * 32;
    constexpr int Nn = NCT * 16;
    const int lane = threadIdx.x & 63;
    const int wave = threadIdx.x >> 6;
    const int rowBase = blk * 128 + wave * 32;
    const int kgrp = (lane >> 4) * 8;

    const float* ap0;
    const float* ap1;
    {
        int r0 = rowBase + (lane & 15);      if (r0 >= M) r0 = M - 1;
        int r1 = rowBase + (lane & 15) + 16; if (r1 >= M) r1 = M - 1;
        ap0 = A + (size_t)r0 * K + kgrp;
        ap1 = A + (size_t)r1 * K + kgrp;
    }

    f32x4 acc[2][NCT] = {};

    float4 c00 = *(const float4*)(ap0);
    float4 c01 = *(const float4*)(ap0 + 4);
    float4 c10 = *(const float4*)(ap1);
    float4 c11 = *(const float4*)(ap1 + 4);

    for (int ks = 0; ks < KS; ++ks) {
        float4 n00, n01, n10, n11;
        if (ks + 1 < KS) {
            const float* p0 = ap0 + (size_t)(ks + 1) * 32;
            const float* p1 = ap1 + (size_t)(ks + 1) * 32;
            n00 = *(const float4*)(p0);
            n01 = *(const float4*)(p0 + 4);
            n10 = *(const float4*)(p1);
            n11 = *(const float4*)(p1 + 4);
        }
        bf16x8 ahi[2], alo[2];
        {
            float av0[8] = {c00.x, c00.y, c00.z, c00.w, c01.x, c01.y, c01.z, c01.w};
            float av1[8] = {c10.x, c10.y, c10.z, c10.w, c11.x, c11.y, c11.z, c11.w};
            #pragma unroll
            for (int j = 0; j < 8; ++j) {
                unsigned h0 = f2bf_rne_u(av0[j]);
                ahi[0][j] = (short)h0;
                alo[0][j] = (short)f2bf_rne_u(av0[j] - bfu2f(h0));
                unsigned h1 = f2bf_rne_u(av1[j]);
                ahi[1][j] = (short)h1;
                alo[1][j] = (short)f2bf_rne_u(av1[j] - bfu2f(h1));
            }
        }
        __builtin_amdgcn_s_setprio(1);
        #pragma unroll
        for (int ct = 0; ct < NCT; ++ct) {
            const short* bp = Bfrag + (size_t)(ks * NCT + ct) * 1024 + lane * 8;
            bf16x8 bhi = *(const bf16x8*)bp;
            bf16x8 blo = *(const bf16x8*)(bp + 512);
            #pragma unroll
            for (int t = 0; t < 2; ++t) {
                acc[t][ct] = __builtin_amdgcn_mfma_f32_16x16x32_bf16(ahi[t], bhi, acc[t][ct], 0, 0, 0);
                acc[t][ct] = __builtin_amdgcn_mfma_f32_16x16x32_bf16(ahi[t], blo, acc[t][ct], 0, 0, 0);
                acc[t][ct] = __builtin_amdgcn_mfma_f32_16x16x32_bf16(alo[t], bhi, acc[t][ct], 0, 0, 0);
            }
        }
        __builtin_amdgcn_s_setprio(0);
        c00 = n00; c01 = n01; c10 = n10; c11 = n11;
    }

    const int drow0 = rowBase + (lane >> 4) * 4;
    #pragma unroll
    for (int t = 0; t < 2; ++t) {
        #pragma unroll
        for (int r = 0; r < 4; ++r) {
            int row = drow0 + t * 16 + r;
            if (row < M) {
                unsigned short* hp = H + (size_t)row * Nn + (lane & 15);
                #pragma unroll
                for (int ct = 0; ct < NCT; ++ct)
                    hp[ct * 16] = (unsigned short)f2bf_rne_u(acc[t][ct][r]);
            }
        }
    }
}

// ================= kernels =================

// K0: [zero deg | bfrag]
__global__ __launch_bounds__(THREADS)
void zero_bfrag_kernel(int* __restrict__ deg, int N,
                       const float* __restrict__ W1, short* __restrict__ bf1,
                       const float* __restrict__ W2, short* __restrict__ bf2, int nbZero) {
    int b = (int)blockIdx.x;
    if (b < nbZero) {
        int base = (b * THREADS + (int)threadIdx.x) * 4;
        if (base + 3 < N) {
            *(int4*)(deg + base) = make_int4(0, 0, 0, 0);
        } else {
            for (int i = base; i < N; ++i) deg[i] = 0;
        }
    } else {
        int u = (b - nbZero) * 4 + ((int)threadIdx.x >> 6);
        int lane = threadIdx.x & 63;
        if (u < 64) bfrag_unit(W1, bf1, 8, u, lane);
        else if (u < 80) bfrag_unit(W2, bf2, 4, u - 64, lane);
    }
}

// K1: [hist || FULL gemm1] Bresenham-interleaved (round-8 proven)
__global__ __launch_bounds__(THREADS)
void hist_gemm1_kernel(const int* __restrict__ dst, int* __restrict__ deg,
                       int* __restrict__ rank, int E,
                       const float* __restrict__ A, const short* __restrict__ Bfrag,
                       unsigned short* __restrict__ H, int M,
                       int nbHist, int nbGemm) {
    int b = (int)blockIdx.x;
    int total = nbHist + nbGemm;
    long long t = (long long)b * nbGemm;
    int gBefore = (int)(t / total);
    bool isG = (((long long)(b + 1) * nbGemm) / total) > gBefore;
    if (isG) gemm_body<8, 8>(A, Bfrag, H, M, gBefore);
    else     hist_body8(dst, deg, rank, E, b - gBefore);
}

// CSR fill, atomic-free, 4 edges/thread
__global__ __launch_bounds__(THREADS)
void fill_col_rank_kernel(const int* __restrict__ src, const int* __restrict__ dst,
                          const int* __restrict__ rank, const int* __restrict__ rowptr,
                          int* __restrict__ col, int E) {
    int base = ((int)blockIdx.x * THREADS + (int)threadIdx.x) * 4;
    if (base + 3 < E) {
        int4 d = *(const int4*)(dst + base);
        int4 r = *(const int4*)(rank + base);
        int4 s = *(const int4*)(src + base);
        col[rowptr[d.x] + r.x] = s.x;
        col[rowptr[d.y] + r.y] = s.y;
        col[rowptr[d.z] + r.z] = s.z;
        col[rowptr[d.w] + r.w] = s.w;
    } else {
        for (int e = base; e < E; ++e)
            col[rowptr[dst[e]] + rank[e]] = src[e];
    }
}

// standalone GEMM (layer 2)
template<int NCT, int KS>
__global__ __launch_bounds__(THREADS)
void mfma_gemm_bf16out_kernel(const float* __restrict__ A, const short* __restrict__ Bfrag,
                              unsigned short* __restrict__ H, int M) {
    gemm_body<NCT, KS>(A, Bfrag, H, M, (int)blockIdx.x);
}

// ================= exclusive scan, fused dis =================

#define SCAN_BLOCK 256
#define SCAN_ITEMS 4   // 1024 elements per block

__global__ __launch_bounds__(SCAN_BLOCK)
void scan_block_kernel(const int* __restrict__ in, int* __restrict__ out,
                       int* __restrict__ blockSums, float* __restrict__ dis, int n) {
    __shared__ int sdata[SCAN_BLOCK];
    int base = blockIdx.x * (SCAN_BLOCK * SCAN_ITEMS);
    int tid = threadIdx.x;
    int v[SCAN_ITEMS];
    int sum = 0;
    #pragma unroll
    for (int k = 0; k < SCAN_ITEMS; ++k) {
        int idx = base + tid * SCAN_ITEMS + k;
        v[k] = (idx < n) ? in[idx] : 0;
        if (idx < n) dis[idx] = rsqrtf((float)v[k] + 1.0f);
        sum += v[k];
    }
    sdata[tid] = sum;
    __syncthreads();
    for (int off = 1; off < SCAN_BLOCK; off <<= 1) {
        int t = (tid >= off) ? sdata[tid - off] : 0;
        __syncthreads();
        sdata[tid] += t;
        __syncthreads();
    }
    if (tid == SCAN_BLOCK - 1) blockSums[blockIdx.x] = sdata[SCAN_BLOCK - 1];
    int run = (tid == 0) ? 0 : sdata[tid - 1];
    #pragma unroll
    for (int k = 0; k < SCAN_ITEMS; ++k) {
        int idx = base + tid * SCAN_ITEMS + k;
        if (idx < n) out[idx] = run;
        run += v[k];
    }
}

__global__ __launch_bounds__(SCAN_BLOCK)
void scan_sums_kernel(int* __restrict__ blockSums, int nB) {
    __shared__ int sdata[SCAN_BLOCK];
    int tid = threadIdx.x;
    sdata[tid] = (tid < nB) ? blockSums[tid] : 0;
    __syncthreads();
    for (int off = 1; off < SCAN_BLOCK; off <<= 1) {
        int t = (tid >= off) ? sdata[tid - off] : 0;
        __syncthreads();
        sdata[tid] += t;
        __syncthreads();
    }
    int excl = (tid == 0) ? 0 : sdata[tid - 1];
    if (tid < nB) blockSums[tid] = excl;
}

__global__ __launch_bounds__(SCAN_BLOCK)
void scan_add_kernel(int* __restrict__ out, const int* __restrict__ blockSums,
                     int n, int E) {
    int base = blockIdx.x * (SCAN_BLOCK * SCAN_ITEMS);
    int add = blockSums[blockIdx.x];
    #pragma unroll
    for (int k = 0; k < SCAN_ITEMS; ++k) {
        int idx = base + threadIdx.x * SCAN_ITEMS + k;
        if (idx < n) out[idx] += add;
    }
    if (blockIdx.x == 0 && threadIdx.x == 0) out[n] = E;
}

// ================= scalarized gather, depth-8 pipeline =================
// out_i = relu(di * (di*h_i + sum_s dis[s]*h_s) + b). One wave per node;
// row base + dis[s] are wave-uniform scalars; up to 16 row loads in flight.

template<int F, int VEC>
__global__ __launch_bounds__(THREADS)
void gather_bf16_kernel(const unsigned short* __restrict__ g, const int* __restrict__ col,
                        const int* __restrict__ rowptr, const float* __restrict__ dis,
                        const float* __restrict__ bias, float* __restrict__ out, int N) {
    int wid = (int)((blockIdx.x * (long long)blockDim.x + threadIdx.x) >> 6);
    wid = __builtin_amdgcn_readfirstlane(wid);
    const int lane = threadIdx.x & 63;
    if (wid >= N) return;
    const float di = dis[wid];
    const int loff = lane * VEC;

    float acc0 = 0.0f, acc1 = 0.0f;

    auto loadrow = [&](int s) -> unsigned {
        const unsigned short* p = g + (size_t)s * F + loff;
        if (VEC == 2) return *(const unsigned*)p;
        else return (unsigned)*p;
    };
    auto addconv = [&](unsigned u, float w) {
        if (VEC == 2) {
            acc0 += w * bfu2f(u & 0xFFFFu);
            acc1 += w * __builtin_bit_cast(float, u & 0xFFFF0000u);
        } else {
            acc0 += w * bfu2f(u);
        }
    };

    addconv(loadrow(wid), di);   // self-loop row

    int start = __builtin_amdgcn_readfirstlane(rowptr[wid]);
    int end   = __builtin_amdgcn_readfirstlane(rowptr[wid + 1]);
    const int* c = col + start;
    int rem = end - start;

    if (rem >= 8) {
        int s0 = __builtin_amdgcn_readfirstlane(c[0]);
        int s1 = __builtin_amdgcn_readfirstlane(c[1]);
        int s2 = __builtin_amdgcn_readfirstlane(c[2]);
        int s3 = __builtin_amdgcn_readfirstlane(c[3]);
        int s4 = __builtin_amdgcn_readfirstlane(c[4]);
        int s5 = __builtin_amdgcn_readfirstlane(c[5]);
        int s6 = __builtin_amdgcn_readfirstlane(c[6]);
        int s7 = __builtin_amdgcn_readfirstlane(c[7]);
        float w0 = dis[s0], w1 = dis[s1], w2 = dis[s2], w3 = dis[s3];
        float w4 = dis[s4], w5 = dis[s5], w6 = dis[s6], w7 = dis[s7];
        unsigned u0 = loadrow(s0), u1 = loadrow(s1), u2 = loadrow(s2), u3 = loadrow(s3);
        unsigned u4 = loadrow(s4), u5 = loadrow(s5), u6 = loadrow(s6), u7 = loadrow(s7);
        c += 8; rem -= 8;
        while (rem >= 8) {
            int t0 = __builtin_amdgcn_readfirstlane(c[0]);
            int t1 = __builtin_amdgcn_readfirstlane(c[1]);
            int t2 = __builtin_amdgcn_readfirstlane(c[2]);
            int t3 = __builtin_amdgcn_readfirstlane(c[3]);
            int t4 = __builtin_amdgcn_readfirstlane(c[4]);
            int t5 = __builtin_amdgcn_readfirstlane(c[5]);
            int t6 = __builtin_amdgcn_readfirstlane(c[6]);
            int t7 = __builtin_amdgcn_readfirstlane(c[7]);
            float x0 = dis[t0], x1 = dis[t1], x2 = dis[t2], x3 = dis[t3];
            float x4 = dis[t4], x5 = dis[t5], x6 = dis[t6], x7 = dis[t7];
            unsigned v0 = loadrow(t0), v1 = loadrow(t1), v2 = loadrow(t2), v3 = loadrow(t3);
            unsigned v4 = loadrow(t4), v5 = loadrow(t5), v6 = loadrow(t6), v7 = loadrow(t7);
            addconv(u0, w0); addconv(u1, w1); addconv(u2, w2); addconv(u3, w3);
            addconv(u4, w4); addconv(u5, w5); addconv(u6, w6); addconv(u7, w7);
            u0 = v0; u1 = v1; u2 = v2; u3 = v3;
            u4 = v4; u5 = v5; u6 = v6; u7 = v7;
            w0 = x0; w1 = x1; w2 = x2; w3 = x3;
            w4 = x4; w5 = x5; w6 = x6; w7 = x7;
            c += 8; rem -= 8;
        }
        addconv(u0, w0); addconv(u1, w1); addconv(u2, w2); addconv(u3, w3);
        addconv(u4, w4); addconv(u5, w5); addconv(u6, w6); addconv(u7, w7);
    }
    if (rem >= 4) {
        int s0 = __builtin_amdgcn_readfirstlane(c[0]);
        int s1 = __builtin_amdgcn_readfirstlane(c[1]);
        int s2 = __builtin_amdgcn_readfirstlane(c[2]);
        int s3 = __builtin_amdgcn_readfirstlane(c[3]);
        float w0 = dis[s0], w1 = dis[s1], w2 = dis[s2], w3 = dis[s3];
        unsigned u0 = loadrow(s0), u1 = loadrow(s1), u2 = loadrow(s2), u3 = loadrow(s3);
        addconv(u0, w0); addconv(u1, w1); addconv(u2, w2); addconv(u3, w3);
        c += 4; rem -= 4;
    }
    while (rem > 0) {
        int s = __builtin_amdgcn_readfirstlane(c[0]);
        addconv(loadrow(s), dis[s]);
        ++c; --rem;
    }

    float* orow = out + (size_t)wid * F + loff;
    float v0 = di * acc0 + bias[loff];
    if (VEC == 2) {
        float v1 = di * acc1 + bias[loff + 1];
        *(float2*)orow = make_float2(fmaxf(v0, 0.0f), fmaxf(v1, 0.0f));
    } else {
        *orow = fmaxf(v0, 0.0f);
    }
}

// ================= fallback fp32 GEMM + atomic path (round-0, verified) =================

#define BM 64
#define BN 64
#define BK 16

__global__ __launch_bounds__(THREADS)
void sgemm_kernel(const float* __restrict__ A, const float* __restrict__ B,
                  float* __restrict__ C, int M, int N, int K) {
    __shared__ float As[BK][BM + 1];
    __shared__ float Bs[BK][BN + 1];

    const int tid = threadIdx.x;
    const int tr = tid / 16;
    const int tc = tid % 16;
    const int rowBase = blockIdx.y * BM;
    const int colBase = blockIdx.x * BN;

    float acc[4][4] = {};

    for (int k0 = 0; k0 < K; k0 += BK) {
        #pragma unroll
        for (int i = tid; i < BM * BK; i += THREADS) {
            int r = i / BK, c = i % BK;
            int gr = rowBase + r;
            As[c][r] = (gr < M) ? A[(size_t)gr * K + k0 + c] : 0.0f;
        }
        #pragma unroll
        for (int i = tid; i < BK * BN; i += THREADS) {
            int r = i / BN, c = i % BN;
            Bs[r][c] = B[(size_t)(k0 + r) * N + colBase + c];
        }
        __syncthreads();

        #pragma unroll
        for (int k = 0; k < BK; ++k) {
            float a[4], b[4];
            #pragma unroll
            for (int m = 0; m < 4; ++m) a[m] = As[k][tr * 4 + m];
            #pragma unroll
            for (int n = 0; n < 4; ++n) b[n] = Bs[k][tc * 4 + n];
            #pragma unroll
            for (int m = 0; m < 4; ++m)
                #pragma unroll
                for (int n = 0; n < 4; ++n)
                    acc[m][n] += a[m] * b[n];
        }
        __syncthreads();
    }

    #pragma unroll
    for (int m = 0; m < 4; ++m) {
        int gr = rowBase + tr * 4 + m;
        if (gr >= M) continue;
        #pragma unroll
        for (int n = 0; n < 4; ++n) {
            C[(size_t)gr * N + colBase + tc * 4 + n] = acc[m][n];
        }
    }
}

__global__ __launch_bounds__(THREADS)
void init_agg_kernel(const float* __restrict__ h, const float* __restrict__ dis,
                     float* __restrict__ agg, int N, int F) {
    int i = blockIdx.x * blockDim.x + threadIdx.x;
    int total = N * (F / 4);
    if (i >= total) return;
    int node = i / (F / 4);
    float d = dis[node];
    float w = d * d;
    float4 v = ((const float4*)h)[i];
    v.x *= w; v.y *= w; v.z *= w; v.w *= w;
    ((float4*)agg)[i] = v;
}

__global__ __launch_bounds__(THREADS)
void edge_scatter_kernel(const float* __restrict__ h, const int* __restrict__ src,
                         const int* __restrict__ dst, const float* __restrict__ dis,
                         float* __restrict__ agg, int E, int F) {
    int lanesPerEdge = F / 4;
    int tid = blockIdx.x * blockDim.x + threadIdx.x;
    int e = tid / lanesPerEdge;
    int c = tid % lanesPerEdge;
    if (e >= E) return;
    int s = src[e];
    int d = dst[e];
    float w = dis[s] * dis[d];
    float4 hv = ((const float4*)(h + (size_t)s * F))[c];
    float* ap = agg + (size_t)d * F + (size_t)c * 4;
    atomicAdd(ap + 0, hv.x * w);
    atomicAdd(ap + 1, hv.y * w);
    atomicAdd(ap + 2, hv.z * w);
    atomicAdd(ap + 3, hv.w * w);
}

__global__ __launch_bounds__(THREADS)
void finalize_kernel(const float* __restrict__ agg, const float* __restrict__ b,
                     float* __restrict__ out, int N, int F) {
    int i = blockIdx.x * blockDim.x + threadIdx.x;
    int total = N * (F / 4);
    if (i >= total) return;
    int c4 = i % (F / 4);
    float4 bv = ((const float4*)b)[c4];
    float4 v = ((const float4*)agg)[i];
    v.x = fmaxf(v.x + bv.x, 0.0f);
    v.y = fmaxf(v.y + bv.y, 0.0f);
    v.z = fmaxf(v.z + bv.z, 0.0f);
    v.w = fmaxf(v.w + bv.w, 0.0f);
    ((float4*)out)[i] = v;
}

__global__ __launch_bounds__(THREADS)
void fdeg_kernel(const int* __restrict__ dst, float* __restrict__ deg, int E) {
    int i = blockIdx.x * blockDim.x + threadIdx.x;
    if (i < E) atomicAdd(&deg[dst[i]], 1.0f);
}

__global__ __launch_bounds__(THREADS)
void fdis_kernel(float* __restrict__ deg, int N) {
    int i = blockIdx.x * blockDim.x + threadIdx.x;
    if (i < N) deg[i] = rsqrtf(deg[i] + 1.0f);
}

// ================= launch =================

extern "C" void kernel_launch(void* const* d_in, const int* in_sizes, int n_in,
                              void* d_out, int out_size, void* d_ws, size_t ws_size,
                              hipStream_t stream) {
    const float* x  = (const float*)d_in[0];
    const int*   ei = (const int*)d_in[1];
    const float* W1 = (const float*)d_in[2];
    const float* b1 = (const float*)d_in[3];
    const float* W2 = (const float*)d_in[4];
    const float* b2 = (const float*)d_in[5];

    const int E    = in_sizes[1] / 2;
    const int hid  = in_sizes[3];            // 128
    const int outc = in_sizes[5];            // 64
    const int inc  = in_sizes[2] / hid;      // 256
    const int N    = in_sizes[0] / inc;      // 100000

    const int* src = ei;
    const int* dst = ei + E;
    float* out = (float*)d_out;
    char* ws = (char*)d_ws;

    auto al = [](size_t v) { return (v + 255) & ~(size_t)255; };
    size_t o_dis  = 0;
    size_t o_deg  = al(o_dis + (size_t)N * 4);
    size_t o_rp   = al(o_deg + (size_t)N * 4);
    size_t o_bs   = al(o_rp + ((size_t)N + 1) * 4);
    size_t o_col  = al(o_bs + 4096);
    size_t o_rank = al(o_col + (size_t)E * 4);
    size_t o_bf1  = al(o_rank + (size_t)E * 4);
    size_t o_bf2  = al(o_bf1 + 131072);                // 8*8*1024 shorts
    size_t o_G    = al(o_bf2 + 32768);                 // 4*4*1024 shorts
    size_t o_B    = al(o_G + (size_t)N * hid * 2);     // h rows (bf16)
    size_t need   = o_B + (size_t)N * hid * 4;         // out1 (fp32)

    if (ws_size >= need && N <= SCAN_BLOCK * SCAN_BLOCK * SCAN_ITEMS &&
        hid == 128 && outc == 64 && inc == 256) {
        // ---------- CSR gather + MFMA path (round-8 structure) ----------
        float* dis    = (float*)(ws + o_dis);
        int*   deg    = (int*)(ws + o_deg);
        int*   rowptr = (int*)(ws + o_rp);
        int*   bsums  = (int*)(ws + o_bs);
        int*   col    = (int*)(ws + o_col);
        int*   rank   = (int*)(ws + o_rank);
        short* bf1    = (short*)(ws + o_bf1);
        short* bf2    = (short*)(ws + o_bf2);
        unsigned short* gbuf = (unsigned short*)(ws + o_G);  // h1 bf16 (N*128), later h2 (N*64)
        float* out1   = (float*)(ws + o_B);     // fp32 layer-1 output

        const int nbZero  = cdiv(N, 4 * THREADS);
        const int nbHist  = cdiv(E, THREADS * HIST_ILP);
        const int nbGemm1 = cdiv(N, 128);
        const int nbFill  = cdiv(E, 4 * THREADS);

        // K0: zero deg || weight fragments
        zero_bfrag_kernel<<<nbZero + 20, THREADS, 0, stream>>>(deg, N, W1, bf1, W2, bf2, nbZero);

        // K1: hist (ILP-8) || FULL gemm1, Bresenham-interleaved
        hist_gemm1_kernel<<<nbHist + nbGemm1, THREADS, 0, stream>>>(
            dst, deg, rank, E, x, bf1, gbuf, N, nbHist, nbGemm1);

        // rowptr = exclusive_scan(deg); dis fused
        int nB = cdiv(N, SCAN_BLOCK * SCAN_ITEMS);
        scan_block_kernel<<<nB, SCAN_BLOCK, 0, stream>>>(deg, rowptr, bsums, dis, N);
        scan_sums_kernel<<<1, SCAN_BLOCK, 0, stream>>>(bsums, nB);
        scan_add_kernel<<<nB, SCAN_BLOCK, 0, stream>>>(rowptr, bsums, N, E);

        // CSR fill (atomic-free)
        fill_col_rank_kernel<<<nbFill, THREADS, 0, stream>>>(src, dst, rank, rowptr, col, E);

        // ---- layer 1 gather (depth-8) ----
        gather_bf16_kernel<128, 2><<<cdiv((long long)N * 64, THREADS), THREADS, 0, stream>>>(
            gbuf, col, rowptr, dis, b1, out1, N);

        // ---- layer 2 ----
        mfma_gemm_bf16out_kernel<4, 4><<<cdiv(N, 128), THREADS, 0, stream>>>(out1, bf2, gbuf, N);
        gather_bf16_kernel<64, 1><<<cdiv((long long)N * 64, THREADS), THREADS, 0, stream>>>(
            gbuf, col, rowptr, dis, b2, out, N);
        return;
    }

    // ---------- fallback: round-0 atomic path ----------
    float* dis = (float*)ws;
    size_t off1 = ((size_t)N * 4 + 255) & ~(size_t)255;
    float* h1 = (float*)(ws + off1);
    size_t off2 = off1 + ((((size_t)N * hid * 4) + 255) & ~(size_t)255);
    float* agg1 = (float*)(ws + off2);
    float* h2   = agg1;
    float* agg2 = agg1 + (size_t)N * outc;

    hipMemsetAsync(dis, 0, (size_t)N * 4, stream);
    fdeg_kernel<<<cdiv(E, THREADS), THREADS, 0, stream>>>(dst, dis, E);
    fdis_kernel<<<cdiv(N, THREADS), THREADS, 0, stream>>>(dis, N);

    {
        dim3 grid(hid / BN, cdiv(N, BM));
        sgemm_kernel<<<grid, THREADS, 0, stream>>>(x, W1, h1, N, hid, inc);
    }
    init_agg_kernel<<<cdiv((long long)N * hid / 4, THREADS), THREADS, 0, stream>>>(h1, dis, agg1, N, hid);
    edge_scatter_kernel<<<cdiv((long long)E * (hid / 4), THREADS), THREADS, 0, stream>>>(
        h1, src, dst, dis, agg1, E, hid);
    finalize_kernel<<<cdiv((long long)N * hid / 4, THREADS), THREADS, 0, stream>>>(agg1, b1, h1, N, hid);

    {
        dim3 grid(outc / BN, cdiv(N, BM));
        sgemm_kernel<<<grid, THREADS, 0, stream>>>(h1, W2, h2, N, outc, hid);
    }
    init_agg_kernel<<<cdiv((long long)N * outc / 4, THREADS), THREADS, 0, stream>>>(h2, dis, agg2, N, outc);
    edge_scatter_kernel<<<cdiv((long long)E * (outc / 4), THREADS), THREADS, 0, stream>>>(
        h2, src, dst, dis, agg2, E, outc);
    finalize_kernel<<<cdiv((long long)N * outc / 4, THREADS), THREADS, 0, stream>>>(agg2, b2, out, N, outc);
}

// Round 13
// 261.965 us; speedup vs baseline: 1.1170x; 1.0394x over previous
//
#include <hip/hip_runtime.h>
#include <math.h>

#define THREADS 256
#define HIST_ILP 8
#define EPB_SHIFT 11   // edges per hist block = THREADS*HIST_ILP = 2048

static inline int cdiv(long long a, long long b) { return (int)((a + b - 1) / b); }

typedef __attribute__((ext_vector_type(8))) short bf16x8;
typedef __attribute__((ext_vector_type(4))) float f32x4;

__device__ inline unsigned f2bf_rne_u(float f) {
    unsigned u = __builtin_bit_cast(unsigned, f);
    return (u + 0x7FFFu + ((u >> 16) & 1u)) >> 16;
}
__device__ inline float bfu2f(unsigned h) {
    unsigned u = h << 16;
    return __builtin_bit_cast(float, u);
}

// ================= device bodies =================

__device__ __forceinline__ void bfrag_unit(const float* __restrict__ W, short* __restrict__ frag,
                                           int NCT, int ctks, int lane) {
    int Nn = NCT * 16;
    int ct = ctks % NCT;
    int ks = ctks / NCT;
    int colc = ct * 16 + (lane & 15);
    int kbase = ks * 32 + (lane >> 4) * 8;
    short* base = frag + (size_t)ctks * 1024 + lane * 8;
    #pragma unroll
    for (int j = 0; j < 8; ++j) {
        float v = W[(size_t)(kbase + j) * Nn + colc];
        unsigned h = f2bf_rne_u(v);
        base[j] = (short)h;
        base[512 + j] = (short)f2bf_rne_u(v - bfu2f(h));
    }
}

// shared-deg histogram + rank, 8 edges/thread
__device__ __forceinline__ void hist_body8(const int* __restrict__ dst, int* __restrict__ deg,
                                           int* __restrict__ rank, int E, int hb) {
    int base = (hb << EPB_SHIFT) + (int)threadIdx.x * HIST_ILP;
    if (base + HIST_ILP - 1 < E) {
        int4 d0 = *(const int4*)(dst + base);
        int4 d1 = *(const int4*)(dst + base + 4);
        int4 r0, r1;
        r0.x = atomicAdd(&deg[d0.x], 1);
        r0.y = atomicAdd(&deg[d0.y], 1);
        r0.z = atomicAdd(&deg[d0.z], 1);
        r0.w = atomicAdd(&deg[d0.w], 1);
        r1.x = atomicAdd(&deg[d1.x], 1);
        r1.y = atomicAdd(&deg[d1.y], 1);
        r1.z = atomicAdd(&deg[d1.z], 1);
        r1.w = atomicAdd(&deg[d1.w], 1);
        *(int4*)(rank + base) = r0;
        *(int4*)(rank + base + 4) = r1;
    } else {
        for (int e = base; e < E; ++e) rank[e] = atomicAdd(&deg[dst[e]], 1);
    }
}

// split-bf16 MFMA GEMM body (round-8 form: no prefetch, no setprio).
// Writes H = bf16(A @ W), unscaled.
template<int NCT, int KS>
__device__ __forceinline__ void gemm_body(const float* __restrict__ A, const short* __restrict__ Bfrag,
                                          unsigned short* __restrict__ H, int M, int blk) {
    constexpr int K = KS * 32;
    constexpr int Nn = NCT * 16;
    const int lane = threadIdx.x & 63;
    const int wave = threadIdx.x >> 6;
    const int rowBase = blk * 128 + wave * 32;
    const int arow0 = rowBase + (lane & 15);
    const int kgrp = (lane >> 4) * 8;

    f32x4 acc[2][NCT] = {};

    for (int ks = 0; ks < KS; ++ks) {
        const int kbase = ks * 32 + kgrp;
        bf16x8 ahi[2], alo[2];
        #pragma unroll
        for (int t = 0; t < 2; ++t) {
            int r = arow0 + t * 16;
            if (r >= M) r = M - 1;   // clamp; rows >= M masked on store
            const float* ap = A + (size_t)r * K + kbase;
            float4 v0 = *(const float4*)ap;
            float4 v1 = *(const float4*)(ap + 4);
            float av[8] = {v0.x, v0.y, v0.z, v0.w, v1.x, v1.y, v1.z, v1.w};
            #pragma unroll
            for (int j = 0; j < 8; ++j) {
                unsigned h = f2bf_rne_u(av[j]);
                ahi[t][j] = (short)h;
                alo[t][j] = (short)f2bf_rne_u(av[j] - bfu2f(h));
            }
        }
        #pragma unroll
        for (int ct = 0; ct < NCT; ++ct) {
            const short* bp = Bfrag + (size_t)(ks * NCT + ct) * 1024 + lane * 8;
            bf16x8 bhi = *(const bf16x8*)bp;
            bf16x8 blo = *(const bf16x8*)(bp + 512);
            #pragma unroll
            for (int t = 0; t < 2; ++t) {
                acc[t][ct] = __builtin_amdgcn_mfma_f32_16x16x32_bf16(ahi[t], bhi, acc[t][ct], 0, 0, 0);
                acc[t][ct] = __builtin_amdgcn_mfma_f32_16x16x32_bf16(ahi[t], blo, acc[t][ct], 0, 0, 0);
                acc[t][ct] = __builtin_amdgcn_mfma_f32_16x16x32_bf16(alo[t], bhi, acc[t][ct], 0, 0, 0);
            }
        }
    }

    // C/D layout: col = lane&15, row(within 16-tile) = (lane>>4)*4 + reg
    const int drow0 = rowBase + (lane >> 4) * 4;
    #pragma unroll
    for (int t = 0; t < 2; ++t) {
        #pragma unroll
        for (int r = 0; r < 4; ++r) {
            int row = drow0 + t * 16 + r;
            if (row < M) {
                unsigned short* hp = H + (size_t)row * Nn + (lane & 15);
                #pragma unroll
                for (int ct = 0; ct < NCT; ++ct)
                    hp[ct * 16] = (unsigned short)f2bf_rne_u(acc[t][ct][r]);
            }
        }
    }
}

// ================= kernels =================

// K0: [zero deg | bfrag]
__global__ __launch_bounds__(THREADS)
void zero_bfrag_kernel(int* __restrict__ deg, int N,
                       const float* __restrict__ W1, short* __restrict__ bf1,
                       const float* __restrict__ W2, short* __restrict__ bf2, int nbZero) {
    int b = (int)blockIdx.x;
    if (b < nbZero) {
        int base = (b * THREADS + (int)threadIdx.x) * 4;
        if (base + 3 < N) {
            *(int4*)(deg + base) = make_int4(0, 0, 0, 0);
        } else {
            for (int i = base; i < N; ++i) deg[i] = 0;
        }
    } else {
        int u = (b - nbZero) * 4 + ((int)threadIdx.x >> 6);
        int lane = threadIdx.x & 63;
        if (u < 64) bfrag_unit(W1, bf1, 8, u, lane);
        else if (u < 80) bfrag_unit(W2, bf2, 4, u - 64, lane);
    }
}

// K1: [hist || FULL gemm1] Bresenham-interleaved (round-8 proven)
__global__ __launch_bounds__(THREADS)
void hist_gemm1_kernel(const int* __restrict__ dst, int* __restrict__ deg,
                       int* __restrict__ rank, int E,
                       const float* __restrict__ A, const short* __restrict__ Bfrag,
                       unsigned short* __restrict__ H, int M,
                       int nbHist, int nbGemm) {
    int b = (int)blockIdx.x;
    int total = nbHist + nbGemm;
    long long t = (long long)b * nbGemm;
    int gBefore = (int)(t / total);
    bool isG = (((long long)(b + 1) * nbGemm) / total) > gBefore;
    if (isG) gemm_body<8, 8>(A, Bfrag, H, M, gBefore);
    else     hist_body8(dst, deg, rank, E, b - gBefore);
}

// CSR fill, atomic-free, 4 edges/thread
__global__ __launch_bounds__(THREADS)
void fill_col_rank_kernel(const int* __restrict__ src, const int* __restrict__ dst,
                          const int* __restrict__ rank, const int* __restrict__ rowptr,
                          int* __restrict__ col, int E) {
    int base = ((int)blockIdx.x * THREADS + (int)threadIdx.x) * 4;
    if (base + 3 < E) {
        int4 d = *(const int4*)(dst + base);
        int4 r = *(const int4*)(rank + base);
        int4 s = *(const int4*)(src + base);
        col[rowptr[d.x] + r.x] = s.x;
        col[rowptr[d.y] + r.y] = s.y;
        col[rowptr[d.z] + r.z] = s.z;
        col[rowptr[d.w] + r.w] = s.w;
    } else {
        for (int e = base; e < E; ++e)
            col[rowptr[dst[e]] + rank[e]] = src[e];
    }
}

// standalone GEMM (layer 2)
template<int NCT, int KS>
__global__ __launch_bounds__(THREADS)
void mfma_gemm_bf16out_kernel(const float* __restrict__ A, const short* __restrict__ Bfrag,
                              unsigned short* __restrict__ H, int M) {
    gemm_body<NCT, KS>(A, Bfrag, H, M, (int)blockIdx.x);
}

// ================= exclusive scan, fused dis =================

#define SCAN_BLOCK 256
#define SCAN_ITEMS 4   // 1024 elements per block

__global__ __launch_bounds__(SCAN_BLOCK)
void scan_block_kernel(const int* __restrict__ in, int* __restrict__ out,
                       int* __restrict__ blockSums, float* __restrict__ dis, int n) {
    __shared__ int sdata[SCAN_BLOCK];
    int base = blockIdx.x * (SCAN_BLOCK * SCAN_ITEMS);
    int tid = threadIdx.x;
    int v[SCAN_ITEMS];
    int sum = 0;
    #pragma unroll
    for (int k = 0; k < SCAN_ITEMS; ++k) {
        int idx = base + tid * SCAN_ITEMS + k;
        v[k] = (idx < n) ? in[idx] : 0;
        if (idx < n) dis[idx] = rsqrtf((float)v[k] + 1.0f);
        sum += v[k];
    }
    sdata[tid] = sum;
    __syncthreads();
    for (int off = 1; off < SCAN_BLOCK; off <<= 1) {
        int t = (tid >= off) ? sdata[tid - off] : 0;
        __syncthreads();
        sdata[tid] += t;
        __syncthreads();
    }
    if (tid == SCAN_BLOCK - 1) blockSums[blockIdx.x] = sdata[SCAN_BLOCK - 1];
    int run = (tid == 0) ? 0 : sdata[tid - 1];
    #pragma unroll
    for (int k = 0; k < SCAN_ITEMS; ++k) {
        int idx = base + tid * SCAN_ITEMS + k;
        if (idx < n) out[idx] = run;
        run += v[k];
    }
}

__global__ __launch_bounds__(SCAN_BLOCK)
void scan_sums_kernel(int* __restrict__ blockSums, int nB) {
    __shared__ int sdata[SCAN_BLOCK];
    int tid = threadIdx.x;
    sdata[tid] = (tid < nB) ? blockSums[tid] : 0;
    __syncthreads();
    for (int off = 1; off < SCAN_BLOCK; off <<= 1) {
        int t = (tid >= off) ? sdata[tid - off] : 0;
        __syncthreads();
        sdata[tid] += t;
        __syncthreads();
    }
    int excl = (tid == 0) ? 0 : sdata[tid - 1];
    if (tid < nB) blockSums[tid] = excl;
}

__global__ __launch_bounds__(SCAN_BLOCK)
void scan_add_kernel(int* __restrict__ out, const int* __restrict__ blockSums,
                     int n, int E) {
    int base = blockIdx.x * (SCAN_BLOCK * SCAN_ITEMS);
    int add = blockSums[blockIdx.x];
    #pragma unroll
    for (int k = 0; k < SCAN_ITEMS; ++k) {
        int idx = base + threadIdx.x * SCAN_ITEMS + k;
        if (idx < n) out[idx] += add;
    }
    if (blockIdx.x == 0 && threadIdx.x == 0) out[n] = E;
}

// ================= scalarized gather, depth-8 pipeline =================
// out_i = relu(di * (di*h_i + sum_s dis[s]*h_s) + b). One wave per node;
// row base + dis[s] are wave-uniform scalars; up to 16 row loads in flight.

template<int F, int VEC>
__global__ __launch_bounds__(THREADS)
void gather_bf16_kernel(const unsigned short* __restrict__ g, const int* __restrict__ col,
                        const int* __restrict__ rowptr, const float* __restrict__ dis,
                        const float* __restrict__ bias, float* __restrict__ out, int N) {
    int wid = (int)((blockIdx.x * (long long)blockDim.x + threadIdx.x) >> 6);
    wid = __builtin_amdgcn_readfirstlane(wid);
    const int lane = threadIdx.x & 63;
    if (wid >= N) return;
    const float di = dis[wid];
    const int loff = lane * VEC;

    float acc0 = 0.0f, acc1 = 0.0f;

    auto loadrow = [&](int s) -> unsigned {
        const unsigned short* p = g + (size_t)s * F + loff;
        if (VEC == 2) return *(const unsigned*)p;
        else return (unsigned)*p;
    };
    auto addconv = [&](unsigned u, float w) {
        if (VEC == 2) {
            acc0 += w * bfu2f(u & 0xFFFFu);
            acc1 += w * __builtin_bit_cast(float, u & 0xFFFF0000u);
        } else {
            acc0 += w * bfu2f(u);
        }
    };

    addconv(loadrow(wid), di);   // self-loop row

    int start = __builtin_amdgcn_readfirstlane(rowptr[wid]);
    int end   = __builtin_amdgcn_readfirstlane(rowptr[wid + 1]);
    const int* c = col + start;
    int rem = end - start;

    if (rem >= 8) {
        int s0 = __builtin_amdgcn_readfirstlane(c[0]);
        int s1 = __builtin_amdgcn_readfirstlane(c[1]);
        int s2 = __builtin_amdgcn_readfirstlane(c[2]);
        int s3 = __builtin_amdgcn_readfirstlane(c[3]);
        int s4 = __builtin_amdgcn_readfirstlane(c[4]);
        int s5 = __builtin_amdgcn_readfirstlane(c[5]);
        int s6 = __builtin_amdgcn_readfirstlane(c[6]);
        int s7 = __builtin_amdgcn_readfirstlane(c[7]);
        float w0 = dis[s0], w1 = dis[s1], w2 = dis[s2], w3 = dis[s3];
        float w4 = dis[s4], w5 = dis[s5], w6 = dis[s6], w7 = dis[s7];
        unsigned u0 = loadrow(s0), u1 = loadrow(s1), u2 = loadrow(s2), u3 = loadrow(s3);
        unsigned u4 = loadrow(s4), u5 = loadrow(s5), u6 = loadrow(s6), u7 = loadrow(s7);
        c += 8; rem -= 8;
        while (rem >= 8) {
            int t0 = __builtin_amdgcn_readfirstlane(c[0]);
            int t1 = __builtin_amdgcn_readfirstlane(c[1]);
            int t2 = __builtin_amdgcn_readfirstlane(c[2]);
            int t3 = __builtin_amdgcn_readfirstlane(c[3]);
            int t4 = __builtin_amdgcn_readfirstlane(c[4]);
            int t5 = __builtin_amdgcn_readfirstlane(c[5]);
            int t6 = __builtin_amdgcn_readfirstlane(c[6]);
            int t7 = __builtin_amdgcn_readfirstlane(c[7]);
            float x0 = dis[t0], x1 = dis[t1], x2 = dis[t2], x3 = dis[t3];
            float x4 = dis[t4], x5 = dis[t5], x6 = dis[t6], x7 = dis[t7];
            unsigned v0 = loadrow(t0), v1 = loadrow(t1), v2 = loadrow(t2), v3 = loadrow(t3);
            unsigned v4 = loadrow(t4), v5 = loadrow(t5), v6 = loadrow(t6), v7 = loadrow(t7);
            addconv(u0, w0); addconv(u1, w1); addconv(u2, w2); addconv(u3, w3);
            addconv(u4, w4); addconv(u5, w5); addconv(u6, w6); addconv(u7, w7);
            u0 = v0; u1 = v1; u2 = v2; u3 = v3;
            u4 = v4; u5 = v5; u6 = v6; u7 = v7;
            w0 = x0; w1 = x1; w2 = x2; w3 = x3;
            w4 = x4; w5 = x5; w6 = x6; w7 = x7;
            c += 8; rem -= 8;
        }
        addconv(u0, w0); addconv(u1, w1); addconv(u2, w2); addconv(u3, w3);
        addconv(u4, w4); addconv(u5, w5); addconv(u6, w6); addconv(u7, w7);
    }
    if (rem >= 4) {
        int s0 = __builtin_amdgcn_readfirstlane(c[0]);
        int s1 = __builtin_amdgcn_readfirstlane(c[1]);
        int s2 = __builtin_amdgcn_readfirstlane(c[2]);
        int s3 = __builtin_amdgcn_readfirstlane(c[3]);
        float w0 = dis[s0], w1 = dis[s1], w2 = dis[s2], w3 = dis[s3];
        unsigned u0 = loadrow(s0), u1 = loadrow(s1), u2 = loadrow(s2), u3 = loadrow(s3);
        addconv(u0, w0); addconv(u1, w1); addconv(u2, w2); addconv(u3, w3);
        c += 4; rem -= 4;
    }
    while (rem > 0) {
        int s = __builtin_amdgcn_readfirstlane(c[0]);
        addconv(loadrow(s), dis[s]);
        ++c; --rem;
    }

    float* orow = out + (size_t)wid * F + loff;
    float v0 = di * acc0 + bias[loff];
    if (VEC == 2) {
        float v1 = di * acc1 + bias[loff + 1];
        *(float2*)orow = make_float2(fmaxf(v0, 0.0f), fmaxf(v1, 0.0f));
    } else {
        *orow = fmaxf(v0, 0.0f);
    }
}

// ================= fallback fp32 GEMM + atomic path (round-0, verified) =================

#define BM 64
#define BN 64
#define BK 16

__global__ __launch_bounds__(THREADS)
void sgemm_kernel(const float* __restrict__ A, const float* __restrict__ B,
                  float* __restrict__ C, int M, int N, int K) {
    __shared__ float As[BK][BM + 1];
    __shared__ float Bs[BK][BN + 1];

    const int tid = threadIdx.x;
    const int tr = tid / 16;
    const int tc = tid % 16;
    const int rowBase = blockIdx.y * BM;
    const int colBase = blockIdx.x * BN;

    float acc[4][4] = {};

    for (int k0 = 0; k0 < K; k0 += BK) {
        #pragma unroll
        for (int i = tid; i < BM * BK; i += THREADS) {
            int r = i / BK, c = i % BK;
            int gr = rowBase + r;
            As[c][r] = (gr < M) ? A[(size_t)gr * K + k0 + c] : 0.0f;
        }
        #pragma unroll
        for (int i = tid; i < BK * BN; i += THREADS) {
            int r = i / BN, c = i % BN;
            Bs[r][c] = B[(size_t)(k0 + r) * N + colBase + c];
        }
        __syncthreads();

        #pragma unroll
        for (int k = 0; k < BK; ++k) {
            float a[4], b[4];
            #pragma unroll
            for (int m = 0; m < 4; ++m) a[m] = As[k][tr * 4 + m];
            #pragma unroll
            for (int n = 0; n < 4; ++n) b[n] = Bs[k][tc * 4 + n];
            #pragma unroll
            for (int m = 0; m < 4; ++m)
                #pragma unroll
                for (int n = 0; n < 4; ++n)
                    acc[m][n] += a[m] * b[n];
        }
        __syncthreads();
    }

    #pragma unroll
    for (int m = 0; m < 4; ++m) {
        int gr = rowBase + tr * 4 + m;
        if (gr >= M) continue;
        #pragma unroll
        for (int n = 0; n < 4; ++n) {
            C[(size_t)gr * N + colBase + tc * 4 + n] = acc[m][n];
        }
    }
}

__global__ __launch_bounds__(THREADS)
void init_agg_kernel(const float* __restrict__ h, const float* __restrict__ dis,
                     float* __restrict__ agg, int N, int F) {
    int i = blockIdx.x * blockDim.x + threadIdx.x;
    int total = N * (F / 4);
    if (i >= total) return;
    int node = i / (F / 4);
    float d = dis[node];
    float w = d * d;
    float4 v = ((const float4*)h)[i];
    v.x *= w; v.y *= w; v.z *= w; v.w *= w;
    ((float4*)agg)[i] = v;
}

__global__ __launch_bounds__(THREADS)
void edge_scatter_kernel(const float* __restrict__ h, const int* __restrict__ src,
                         const int* __restrict__ dst, const float* __restrict__ dis,
                         float* __restrict__ agg, int E, int F) {
    int lanesPerEdge = F / 4;
    int tid = blockIdx.x * blockDim.x + threadIdx.x;
    int e = tid / lanesPerEdge;
    int c = tid % lanesPerEdge;
    if (e >= E) return;
    int s = src[e];
    int d = dst[e];
    float w = dis[s] * dis[d];
    float4 hv = ((const float4*)(h + (size_t)s * F))[c];
    float* ap = agg + (size_t)d * F + (size_t)c * 4;
    atomicAdd(ap + 0, hv.x * w);
    atomicAdd(ap + 1, hv.y * w);
    atomicAdd(ap + 2, hv.z * w);
    atomicAdd(ap + 3, hv.w * w);
}

__global__ __launch_bounds__(THREADS)
void finalize_kernel(const float* __restrict__ agg, const float* __restrict__ b,
                     float* __restrict__ out, int N, int F) {
    int i = blockIdx.x * blockDim.x + threadIdx.x;
    int total = N * (F / 4);
    if (i >= total) return;
    int c4 = i % (F / 4);
    float4 bv = ((const float4*)b)[c4];
    float4 v = ((const float4*)agg)[i];
    v.x = fmaxf(v.x + bv.x, 0.0f);
    v.y = fmaxf(v.y + bv.y, 0.0f);
    v.z = fmaxf(v.z + bv.z, 0.0f);
    v.w = fmaxf(v.w + bv.w, 0.0f);
    ((float4*)out)[i] = v;
}

__global__ __launch_bounds__(THREADS)
void fdeg_kernel(const int* __restrict__ dst, float* __restrict__ deg, int E) {
    int i = blockIdx.x * blockDim.x + threadIdx.x;
    if (i < E) atomicAdd(&deg[dst[i]], 1.0f);
}

__global__ __launch_bounds__(THREADS)
void fdis_kernel(float* __restrict__ deg, int N) {
    int i = blockIdx.x * blockDim.x + threadIdx.x;
    if (i < N) deg[i] = rsqrtf(deg[i] + 1.0f);
}

// ================= launch =================

extern "C" void kernel_launch(void* const* d_in, const int* in_sizes, int n_in,
                              void* d_out, int out_size, void* d_ws, size_t ws_size,
                              hipStream_t stream) {
    const float* x  = (const float*)d_in[0];
    const int*   ei = (const int*)d_in[1];
    const float* W1 = (const float*)d_in[2];
    const float* b1 = (const float*)d_in[3];
    const float* W2 = (const float*)d_in[4];
    const float* b2 = (const float*)d_in[5];

    const int E    = in_sizes[1] / 2;
    const int hid  = in_sizes[3];            // 128
    const int outc = in_sizes[5];            // 64
    const int inc  = in_sizes[2] / hid;      // 256
    const int N    = in_sizes[0] / inc;      // 100000

    const int* src = ei;
    const int* dst = ei + E;
    float* out = (float*)d_out;
    char* ws = (char*)d_ws;

    auto al = [](size_t v) { return (v + 255) & ~(size_t)255; };
    size_t o_dis  = 0;
    size_t o_deg  = al(o_dis + (size_t)N * 4);
    size_t o_rp   = al(o_deg + (size_t)N * 4);
    size_t o_bs   = al(o_rp + ((size_t)N + 1) * 4);
    size_t o_col  = al(o_bs + 4096);
    size_t o_rank = al(o_col + (size_t)E * 4);
    size_t o_bf1  = al(o_rank + (size_t)E * 4);
    size_t o_bf2  = al(o_bf1 + 131072);                // 8*8*1024 shorts
    size_t o_G    = al(o_bf2 + 32768);                 // 4*4*1024 shorts
    size_t o_B    = al(o_G + (size_t)N * hid * 2);     // h rows (bf16)
    size_t need   = o_B + (size_t)N * hid * 4;         // out1 (fp32)

    if (ws_size >= need && N <= SCAN_BLOCK * SCAN_BLOCK * SCAN_ITEMS &&
        hid == 128 && outc == 64 && inc == 256) {
        // ---------- CSR gather + MFMA path (round-8 structure) ----------
        float* dis    = (float*)(ws + o_dis);
        int*   deg    = (int*)(ws + o_deg);
        int*   rowptr = (int*)(ws + o_rp);
        int*   bsums  = (int*)(ws + o_bs);
        int*   col    = (int*)(ws + o_col);
        int*   rank   = (int*)(ws + o_rank);
        short* bf1    = (short*)(ws + o_bf1);
        short* bf2    = (short*)(ws + o_bf2);
        unsigned short* gbuf = (unsigned short*)(ws + o_G);  // h1 bf16 (N*128), later h2 (N*64)
        float* out1   = (float*)(ws + o_B);     // fp32 layer-1 output

        const int nbZero  = cdiv(N, 4 * THREADS);
        const int nbHist  = cdiv(E, THREADS * HIST_ILP);
        const int nbGemm1 = cdiv(N, 128);
        const int nbFill  = cdiv(E, 4 * THREADS);

        // K0: zero deg || weight fragments
        zero_bfrag_kernel<<<nbZero + 20, THREADS, 0, stream>>>(deg, N, W1, bf1, W2, bf2, nbZero);

        // K1: hist (ILP-8) || FULL gemm1, Bresenham-interleaved
        hist_gemm1_kernel<<<nbHist + nbGemm1, THREADS, 0, stream>>>(
            dst, deg, rank, E, x, bf1, gbuf, N, nbHist, nbGemm1);

        // rowptr = exclusive_scan(deg); dis fused
        int nB = cdiv(N, SCAN_BLOCK * SCAN_ITEMS);
        scan_block_kernel<<<nB, SCAN_BLOCK, 0, stream>>>(deg, rowptr, bsums, dis, N);
        scan_sums_kernel<<<1, SCAN_BLOCK, 0, stream>>>(bsums, nB);
        scan_add_kernel<<<nB, SCAN_BLOCK, 0, stream>>>(rowptr, bsums, N, E);

        // CSR fill (atomic-free)
        fill_col_rank_kernel<<<nbFill, THREADS, 0, stream>>>(src, dst, rank, rowptr, col, E);

        // ---- layer 1 gather (depth-8) ----
        gather_bf16_kernel<128, 2><<<cdiv((long long)N * 64, THREADS), THREADS, 0, stream>>>(
            gbuf, col, rowptr, dis, b1, out1, N);

        // ---- layer 2 ----
        mfma_gemm_bf16out_kernel<4, 4><<<cdiv(N, 128), THREADS, 0, stream>>>(out1, bf2, gbuf, N);
        gather_bf16_kernel<64, 1><<<cdiv((long long)N * 64, THREADS), THREADS, 0, stream>>>(
            gbuf, col, rowptr, dis, b2, out, N);
        return;
    }

    // ---------- fallback: round-0 atomic path ----------
    float* dis = (float*)ws;
    size_t off1 = ((size_t)N * 4 + 255) & ~(size_t)255;
    float* h1 = (float*)(ws + off1);
    size_t off2 = off1 + ((((size_t)N * hid * 4) + 255) & ~(size_t)255);
    float* agg1 = (float*)(ws + off2);
    float* h2   = agg1;
    float* agg2 = agg1 + (size_t)N * outc;

    hipMemsetAsync(dis, 0, (size_t)N * 4, stream);
    fdeg_kernel<<<cdiv(E, THREADS), THREADS, 0, stream>>>(dst, dis, E);
    fdis_kernel<<<cdiv(N, THREADS), THREADS, 0, stream>>>(dis, N);

    {
        dim3 grid(hid / BN, cdiv(N, BM));
        sgemm_kernel<<<grid, THREADS, 0, stream>>>(x, W1, h1, N, hid, inc);
    }
    init_agg_kernel<<<cdiv((long long)N * hid / 4, THREADS), THREADS, 0, stream>>>(h1, dis, agg1, N, hid);
    edge_scatter_kernel<<<cdiv((long long)E * (hid / 4), THREADS), THREADS, 0, stream>>>(
        h1, src, dst, dis, agg1, E, hid);
    finalize_kernel<<<cdiv((long long)N * hid / 4, THREADS), THREADS, 0, stream>>>(agg1, b1, h1, N, hid);

    {
        dim3 grid(outc / BN, cdiv(N, BM));
        sgemm_kernel<<<grid, THREADS, 0, stream>>>(h1, W2, h2, N, outc, hid);
    }
    init_agg_kernel<<<cdiv((long long)N * outc / 4, THREADS), THREADS, 0, stream>>>(h2, dis, agg2, N, outc);
    edge_scatter_kernel<<<cdiv((long long)E * (outc / 4), THREADS), THREADS, 0, stream>>>(
        h2, src, dst, dis, agg2, E, outc);
    finalize_kernel<<<cdiv((long long)N * outc / 4, THREADS), THREADS, 0, stream>>>(agg2, b2, out, N, outc);
}